// Round 7
// baseline (319.858 us; speedup 1.0000x reference)
//
#include <hip/hip_runtime.h>
#include <hip/hip_bf16.h>

// GCN x3 + FC on a fixed random graph.
//   1. Bucket-partition CSR build: hist -> scan -> packed partition
//      (src|dl<<18) -> per-bucket build (LDS atomics, coalesced I/O) with
//      fused prescale y0 = dinv*x (fp16).
//   2. Pull aggregation over pre-scaled features y = dinv*h:
//      out[v] = dinv[v]*(sum y[s] + y[v]).  All inter-layer features fp16.
//   3. R14: DEGREE-SORTED work assignment.  R13 showed aggs are divergence-
//      shaped latency-bound: wave trip count = max(deg) over its nodes
//      (~15-18 for Poisson(8)) while median lane needs 8; 2.5x latency slack
//      vs BW floor (aggt2: 17us floor, 42us measured).  Fix: perm[] sorts
//      nodes by degree (64 buckets); agg kernels process rank order with
//      sequential offp/dinvp; same-degree waves -> trips ~= deg.  Feature
//      arrays stay in ORIGINAL id order (adj needs no translation); self
//      reads + y1/y2 writes become scattered (acceptable sector waste).
//      agg3 writes a3 in RANK order (sequential); t3fc scatters final 256B
//      rows via perm (aligned, no waste).
//   4. t3fc (R10): MFMA mfma_f32_16x16x32_f16; weights pre-converted to
//      B-frag-ordered fp16 in bscan; per-wave 2KB LDS relu scratch.

#define NB   256     // dst buckets
#define NPB  1024    // nodes per bucket (N = NB*NPB)
#define TILE 4096    // edges per partition tile
#define SRCMASK 0x3FFFFu
#define DB   64      // degree buckets

typedef _Float16 half8 __attribute__((ext_vector_type(8)));
typedef float float4v __attribute__((ext_vector_type(4)));

__device__ __forceinline__ unsigned pkh(float a, float b) {  // 2x fp32 -> packed fp16 (RNE)
    unsigned short ua = __builtin_bit_cast(unsigned short, (_Float16)a);
    unsigned short ub = __builtin_bit_cast(unsigned short, (_Float16)b);
    return (unsigned)ua | ((unsigned)ub << 16);
}
__device__ __forceinline__ float h_lo(unsigned u) {
    return (float)__builtin_bit_cast(_Float16, (unsigned short)(u & 0xFFFFu));
}
__device__ __forceinline__ float h_hi(unsigned u) {
    return (float)__builtin_bit_cast(_Float16, (unsigned short)(u >> 16));
}

#define UNPK8_ADD(A, u) \
    A##0 += h_lo(u.x); A##1 += h_hi(u.x); A##2 += h_lo(u.y); A##3 += h_hi(u.y); \
    A##4 += h_lo(u.z); A##5 += h_hi(u.z); A##6 += h_lo(u.w); A##7 += h_hi(u.w);

// ---- P1: global bucket histogram -------------------------------------------
__global__ void hist_kernel(const int* __restrict__ dst, int* __restrict__ ghist,
                            int E, int shift) {
    __shared__ int h[NB];
    int tid = threadIdx.x;
    h[tid] = 0;
    __syncthreads();
    int base = blockIdx.x * TILE;
    int cnt = min(TILE, E - base);
    for (int i = tid; i < cnt; i += 256)
        atomicAdd(&h[dst[base + i] >> shift], 1);
    __syncthreads();
    int v = h[tid];
    if (v) atomicAdd(&ghist[tid], v);
}

// ---- P2: scan bucket counts + zero dhist + weight->fp16 frag conversion ----
__global__ void bscan_kernel(const int* __restrict__ ghist, int* __restrict__ bbase,
                             int* __restrict__ gcursor, int* __restrict__ dhist,
                             const float* __restrict__ W3, const float* __restrict__ Wf,
                             _Float16* __restrict__ w3f, _Float16* __restrict__ wff) {
    __shared__ int sh[NB];
    int tid = threadIdx.x;
    if (tid < DB) dhist[tid] = 0;
    int v = ghist[tid];
    sh[tid] = v;
    __syncthreads();
    for (int o = 1; o < NB; o <<= 1) {
        int t = (tid >= o) ? sh[tid - o] : 0;
        __syncthreads();
        sh[tid] += t;
        __syncthreads();
    }
    int incl = sh[tid];
    bbase[tid] = incl - v;
    gcursor[tid] = incl - v;
    if (tid == NB - 1) bbase[NB] = incl;
    // W3: [32][64]
    for (int i = tid; i < 32 * 64; i += NB) {
        int k = i >> 6, j = i & 63;
        w3f[(j >> 4) * 512 + (j & 15) * 32 + (k >> 3) * 8 + (k & 7)] = (_Float16)W3[i];
    }
    // Wf: [64][64]
    for (int i = tid; i < 64 * 64; i += NB) {
        int k = i >> 6, j = i & 63;
        wff[((k >> 5) * 4 + (j >> 4)) * 512 + (j & 15) * 32 + ((k >> 3) & 3) * 8 + (k & 7)]
            = (_Float16)Wf[i];
    }
}

// ---- P3: partition edges into bucket-contiguous packed stream --------------
__global__ void __launch_bounds__(256)
partition_kernel(const int* __restrict__ src, const int* __restrict__ dst,
                 int* __restrict__ gcursor, unsigned int* __restrict__ bedge,
                 int E, int shift, int mask) {
    __shared__ int h[NB], st[NB], gp[NB];
    __shared__ unsigned short rk[TILE];
    __shared__ int sd[TILE];
    __shared__ int ss[TILE];
    int tid = threadIdx.x;
    h[tid] = 0;
    __syncthreads();
    int base = blockIdx.x * TILE;
    int cnt = min(TILE, E - base);
    for (int i = tid; i < cnt; i += 256)
        rk[i] = (unsigned short)atomicAdd(&h[dst[base + i] >> shift], 1);
    __syncthreads();
    int hv = h[tid];
    st[tid] = hv;
    __syncthreads();
    for (int o = 1; o < NB; o <<= 1) {
        int t = (tid >= o) ? st[tid - o] : 0;
        __syncthreads();
        st[tid] += t;
        __syncthreads();
    }
    st[tid] -= hv;
    gp[tid] = hv ? atomicAdd(&gcursor[tid], hv) : 0;
    __syncthreads();
    for (int i = tid; i < cnt; i += 256) {
        int d = dst[base + i];
        int b = d >> shift;
        int pos = st[b] + rk[i];
        sd[pos] = d;
        ss[pos] = src[base + i];
    }
    __syncthreads();
    for (int i = tid; i < cnt; i += 256) {
        int d = sd[i];
        int b = d >> shift;
        int g = gp[b] + (i - st[b]);
        bedge[g] = (unsigned int)ss[i] | ((unsigned int)(d & mask) << 18);
    }
}

// ---- P4: per-bucket CSR build + fused prescale (fp16 y0) + degree hist -----
__global__ void __launch_bounds__(256)
build_kernel(const int* __restrict__ bbase, const unsigned int* __restrict__ bedge,
             const float* __restrict__ x,
             int* __restrict__ off, float* __restrict__ dinv, int* __restrict__ adj,
             _Float16* __restrict__ y0h, int* __restrict__ dhist) {
    __shared__ int deg1[NPB];
    __shared__ int cur[NPB];
    __shared__ int bs[256];
    __shared__ int dh[DB];
    int tid = threadIdx.x;
    int b = blockIdx.x;
    int s = bbase[b], e = bbase[b + 1];
    int base = tid * 4;
#pragma unroll
    for (int i = 0; i < 4; i++) deg1[base + i] = 0;
    if (tid < DB) dh[tid] = 0;
    __syncthreads();
    for (int i = s + tid; i < e; i += 256)
        atomicAdd(&deg1[bedge[i] >> 18], 1);
    __syncthreads();
    int d0 = deg1[base], d1 = deg1[base + 1], d2 = deg1[base + 2], d3 = deg1[base + 3];
    atomicAdd(&dh[min(d0, DB - 1)], 1); atomicAdd(&dh[min(d1, DB - 1)], 1);
    atomicAdd(&dh[min(d2, DB - 1)], 1); atomicAdd(&dh[min(d3, DB - 1)], 1);
    int th = d0 + d1 + d2 + d3;
    bs[tid] = th;
    __syncthreads();
    for (int o = 1; o < 256; o <<= 1) {
        int t = (tid >= o) ? bs[tid - o] : 0;
        __syncthreads();
        bs[tid] += t;
        __syncthreads();
    }
    int run = s + bs[tid] - th;
    int vb = b * NPB + base;
    off[vb]     = run; cur[base]     = run; dinv[vb]     = rsqrtf((float)(d0 + 1)); run += d0;
    off[vb + 1] = run; cur[base + 1] = run; dinv[vb + 1] = rsqrtf((float)(d1 + 1)); run += d1;
    off[vb + 2] = run; cur[base + 2] = run; dinv[vb + 2] = rsqrtf((float)(d2 + 1)); run += d2;
    off[vb + 3] = run; cur[base + 3] = run; dinv[vb + 3] = rsqrtf((float)(d3 + 1)); run += d3;
    if (b == NB - 1 && tid == 255) off[NB * NPB] = e;   // sentinel off[N] = E
    if (tid < DB && dh[tid]) atomicAdd(&dhist[tid], dh[tid]);
    __syncthreads();
    for (int i = s + tid; i < e; i += 256) {
        unsigned int pk = bedge[i];
        int p = atomicAdd(&cur[pk >> 18], 1);
        adj[p] = (int)(pk & SRCMASK);
    }
    // fused prescale: y0h[v] = fp16(dinv[v] * x[v])  (bucket rows, coalesced)
    for (int i = tid; i < NPB; i += 256) {
        float dv = rsqrtf((float)(deg1[i] + 1));
        const float4* xr = (const float4*)x + (size_t)(b * NPB + i) * 2;
        float4 t0 = xr[0], t1 = xr[1];
        uint4 pk;
        pk.x = pkh(t0.x * dv, t0.y * dv); pk.y = pkh(t0.z * dv, t0.w * dv);
        pk.z = pkh(t1.x * dv, t1.y * dv); pk.w = pkh(t1.z * dv, t1.w * dv);
        ((uint4*)y0h)[(size_t)b * NPB + i] = pk;
    }
}

// ---- P5: scan degree hist -> dcur ------------------------------------------
__global__ void dscan_kernel(const int* __restrict__ dhist, int* __restrict__ dcur) {
    __shared__ int sh[DB];
    int tid = threadIdx.x;
    int v = dhist[tid];
    sh[tid] = v;
    __syncthreads();
    for (int o = 1; o < DB; o <<= 1) {
        int t = (tid >= o) ? sh[tid - o] : 0;
        __syncthreads();
        sh[tid] += t;
        __syncthreads();
    }
    dcur[tid] = sh[tid] - v;   // exclusive base
}

// ---- P6: scatter nodes into degree-sorted rank order -----------------------
// perm[r] = node, offp[r] = (beg,end), dinvp[r] = dinv  (sequential reads in aggs)
__global__ void __launch_bounds__(256)
dscatter_kernel(const int* __restrict__ off, const float* __restrict__ dinv,
                int* __restrict__ dcur, int* __restrict__ perm,
                uint2* __restrict__ offp, float* __restrict__ dinvp) {
    __shared__ unsigned short rk[1024];
    __shared__ unsigned char dgs[1024];
    __shared__ int lh[DB], gb[DB];
    const int tid = threadIdx.x;
    const int vb = blockIdx.x * 1024;
    if (tid < DB) lh[tid] = 0;
    __syncthreads();
    for (int ln = tid; ln < 1024; ln += 256) {
        int v = vb + ln;
        int d = min(off[v + 1] - off[v], DB - 1);
        dgs[ln] = (unsigned char)d;
        rk[ln] = (unsigned short)atomicAdd(&lh[d], 1);
    }
    __syncthreads();
    if (tid < DB) gb[tid] = lh[tid] ? atomicAdd(&dcur[tid], lh[tid]) : 0;
    __syncthreads();
    for (int ln = tid; ln < 1024; ln += 256) {
        int v = vb + ln;
        int g = gb[dgs[ln]] + rk[ln];
        perm[g] = v;
        uint2 oo; oo.x = (unsigned)off[v]; oo.y = (unsigned)off[v + 1];
        offp[g] = oo;
        dinvp[g] = dinv[v];
    }
}

// ---- Fused agg(8-dim fp16) + transform 8->16 -> fp16 y1 (rank order) -------
__global__ void __launch_bounds__(256)
aggt1_kernel(const _Float16* __restrict__ y0h, const uint2* __restrict__ offp,
             const int* __restrict__ adj, const float* __restrict__ dinvp,
             const int* __restrict__ perm,
             const float* __restrict__ W1, const float* __restrict__ b1,
             _Float16* __restrict__ y1h) {
    __shared__ float Ws[8 * 16];
    __shared__ float bsh[16];
    const int tid = threadIdx.x;
    if (tid < 128) Ws[tid] = W1[tid];
    if (tid < 16) bsh[tid] = b1[tid];
    const int r = blockIdx.x * 256 + tid;
    const int pv = perm[r];
    const uint2 oo = offp[r];
    const uint4* y4 = (const uint4*)y0h;
    int beg = (int)oo.x, end = (int)oo.y;
    uint4 us = y4[pv];   // self (full row)
    float a0 = h_lo(us.x), a1 = h_hi(us.x), a2 = h_lo(us.y), a3 = h_hi(us.y),
          a4 = h_lo(us.z), a5 = h_hi(us.z), a6 = h_lo(us.w), a7 = h_hi(us.w);
    float c0 = 0, c1 = 0, c2 = 0, c3 = 0, c4 = 0, c5 = 0, c6 = 0, c7 = 0;
    int e = beg;
    for (; e + 8 <= end; e += 8) {
        int s0 = adj[e], s1 = adj[e + 1], s2 = adj[e + 2], s3 = adj[e + 3];
        int s4 = adj[e + 4], s5 = adj[e + 5], s6 = adj[e + 6], s7 = adj[e + 7];
        uint4 u0 = y4[s0], u1 = y4[s1], u2 = y4[s2], u3 = y4[s3];
        uint4 u4 = y4[s4], u5 = y4[s5], u6 = y4[s6], u7 = y4[s7];
        UNPK8_ADD(a, u0) UNPK8_ADD(c, u1) UNPK8_ADD(a, u2) UNPK8_ADD(c, u3)
        UNPK8_ADD(a, u4) UNPK8_ADD(c, u5) UNPK8_ADD(a, u6) UNPK8_ADD(c, u7)
    }
    for (; e + 2 <= end; e += 2) {
        int s0 = adj[e], s1 = adj[e + 1];
        uint4 u0 = y4[s0], u1 = y4[s1];
        UNPK8_ADD(a, u0) UNPK8_ADD(c, u1)
    }
    if (e < end) {
        uint4 u0 = y4[adj[e]];
        UNPK8_ADD(a, u0)
    }
    float dv = dinvp[r];
    float in[8];
    in[0] = (a0 + c0) * dv; in[1] = (a1 + c1) * dv;
    in[2] = (a2 + c2) * dv; in[3] = (a3 + c3) * dv;
    in[4] = (a4 + c4) * dv; in[5] = (a5 + c5) * dv;
    in[6] = (a6 + c6) * dv; in[7] = (a7 + c7) * dv;
    __syncthreads();   // Ws/bsh visibility
    const float4* W4 = (const float4*)Ws;
    float o[16];
    {
        float4 b0 = ((const float4*)bsh)[0], b1v = ((const float4*)bsh)[1];
        float4 b2v = ((const float4*)bsh)[2], b3v = ((const float4*)bsh)[3];
        o[0] = b0.x; o[1] = b0.y; o[2] = b0.z; o[3] = b0.w;
        o[4] = b1v.x; o[5] = b1v.y; o[6] = b1v.z; o[7] = b1v.w;
        o[8] = b2v.x; o[9] = b2v.y; o[10] = b2v.z; o[11] = b2v.w;
        o[12] = b3v.x; o[13] = b3v.y; o[14] = b3v.z; o[15] = b3v.w;
    }
#pragma unroll
    for (int k = 0; k < 8; k++) {
        float xk = in[k];
        float4 w0 = W4[k * 4 + 0], w1 = W4[k * 4 + 1];
        float4 w2 = W4[k * 4 + 2], w3 = W4[k * 4 + 3];
        o[0] = fmaf(xk, w0.x, o[0]);  o[1] = fmaf(xk, w0.y, o[1]);
        o[2] = fmaf(xk, w0.z, o[2]);  o[3] = fmaf(xk, w0.w, o[3]);
        o[4] = fmaf(xk, w1.x, o[4]);  o[5] = fmaf(xk, w1.y, o[5]);
        o[6] = fmaf(xk, w1.z, o[6]);  o[7] = fmaf(xk, w1.w, o[7]);
        o[8] = fmaf(xk, w2.x, o[8]);  o[9] = fmaf(xk, w2.y, o[9]);
        o[10] = fmaf(xk, w2.z, o[10]); o[11] = fmaf(xk, w2.w, o[11]);
        o[12] = fmaf(xk, w3.x, o[12]); o[13] = fmaf(xk, w3.y, o[13]);
        o[14] = fmaf(xk, w3.z, o[14]); o[15] = fmaf(xk, w3.w, o[15]);
    }
    uint4 p0, p1;
    p0.x = pkh(dv * fmaxf(o[0], 0.f),  dv * fmaxf(o[1], 0.f));
    p0.y = pkh(dv * fmaxf(o[2], 0.f),  dv * fmaxf(o[3], 0.f));
    p0.z = pkh(dv * fmaxf(o[4], 0.f),  dv * fmaxf(o[5], 0.f));
    p0.w = pkh(dv * fmaxf(o[6], 0.f),  dv * fmaxf(o[7], 0.f));
    p1.x = pkh(dv * fmaxf(o[8], 0.f),  dv * fmaxf(o[9], 0.f));
    p1.y = pkh(dv * fmaxf(o[10], 0.f), dv * fmaxf(o[11], 0.f));
    p1.z = pkh(dv * fmaxf(o[12], 0.f), dv * fmaxf(o[13], 0.f));
    p1.w = pkh(dv * fmaxf(o[14], 0.f), dv * fmaxf(o[15], 0.f));
    uint4* out4 = (uint4*)y1h;
    out4[(size_t)pv * 2]     = p0;
    out4[(size_t)pv * 2 + 1] = p1;
}

// ---- Fused agg(16-dim fp16) + transform 16->32 -> fp16 y2 (rank order) -----
__global__ void __launch_bounds__(256)
aggt2_kernel(const _Float16* __restrict__ y1h, const uint2* __restrict__ offp,
             const int* __restrict__ adj, const float* __restrict__ dinvp,
             const int* __restrict__ perm,
             const float* __restrict__ W2, const float* __restrict__ b2,
             unsigned int* __restrict__ y2b) {
    __shared__ float Ws[16 * 32];
    __shared__ float bsh[32];
    const int tid = threadIdx.x;
    for (int i = tid; i < 16 * 32; i += 256) Ws[i] = W2[i];
    if (tid < 32) bsh[tid] = b2[tid];
    const int vl = tid >> 1, c = tid & 1;
    const int r = blockIdx.x * 128 + vl;
    const int pv = perm[r];
    const uint2 oo = offp[r];
    const uint4* y4 = (const uint4*)y1h;
    int beg = (int)oo.x, end = (int)oo.y;
    uint4 us = y4[(size_t)pv * 2 + c];   // self half-row
    float a0 = h_lo(us.x), a1 = h_hi(us.x), a2 = h_lo(us.y), a3 = h_hi(us.y),
          a4 = h_lo(us.z), a5 = h_hi(us.z), a6 = h_lo(us.w), a7 = h_hi(us.w);
    float c0 = 0, c1 = 0, c2 = 0, c3 = 0, c4 = 0, c5 = 0, c6 = 0, c7 = 0;
    int e = beg;
    for (; e + 8 <= end; e += 8) {
        int s0 = adj[e], s1 = adj[e + 1], s2 = adj[e + 2], s3 = adj[e + 3];
        int s4 = adj[e + 4], s5 = adj[e + 5], s6 = adj[e + 6], s7 = adj[e + 7];
        uint4 u0 = y4[(size_t)s0 * 2 + c], u1 = y4[(size_t)s1 * 2 + c];
        uint4 u2 = y4[(size_t)s2 * 2 + c], u3 = y4[(size_t)s3 * 2 + c];
        uint4 u4 = y4[(size_t)s4 * 2 + c], u5 = y4[(size_t)s5 * 2 + c];
        uint4 u6 = y4[(size_t)s6 * 2 + c], u7 = y4[(size_t)s7 * 2 + c];
        UNPK8_ADD(a, u0) UNPK8_ADD(c, u1) UNPK8_ADD(a, u2) UNPK8_ADD(c, u3)
        UNPK8_ADD(a, u4) UNPK8_ADD(c, u5) UNPK8_ADD(a, u6) UNPK8_ADD(c, u7)
    }
    for (; e + 2 <= end; e += 2) {
        int s0 = adj[e], s1 = adj[e + 1];
        uint4 u0 = y4[(size_t)s0 * 2 + c], u1 = y4[(size_t)s1 * 2 + c];
        UNPK8_ADD(a, u0) UNPK8_ADD(c, u1)
    }
    if (e < end) {
        uint4 u0 = y4[(size_t)adj[e] * 2 + c];
        UNPK8_ADD(a, u0)
    }
    float dv = dinvp[r];
    float own[8];
    own[0] = (a0 + c0) * dv; own[1] = (a1 + c1) * dv;
    own[2] = (a2 + c2) * dv; own[3] = (a3 + c3) * dv;
    own[4] = (a4 + c4) * dv; own[5] = (a5 + c5) * dv;
    own[6] = (a6 + c6) * dv; own[7] = (a7 + c7) * dv;
    float oth[8];
#pragma unroll
    for (int k = 0; k < 8; k++) oth[k] = __shfl_xor(own[k], 1);
    float in[16];
#pragma unroll
    for (int k = 0; k < 8; k++) {
        in[c * 8 + k] = own[k];
        in[(1 - c) * 8 + k] = oth[k];
    }
    __syncthreads();   // Ws/bsh visibility
    const int j0 = c * 16;
    const float4* W4 = (const float4*)Ws;   // 8 float4 per k-row
    float o[16];
#pragma unroll
    for (int jj = 0; jj < 16; jj += 4) {
        float4 bv = *(const float4*)&bsh[j0 + jj];
        o[jj] = bv.x; o[jj + 1] = bv.y; o[jj + 2] = bv.z; o[jj + 3] = bv.w;
    }
#pragma unroll
    for (int k = 0; k < 16; k++) {
        float xk = in[k];
        float4 w0 = W4[k * 8 + c * 4 + 0], w1 = W4[k * 8 + c * 4 + 1];
        float4 w2 = W4[k * 8 + c * 4 + 2], w3 = W4[k * 8 + c * 4 + 3];
        o[0] = fmaf(xk, w0.x, o[0]);  o[1] = fmaf(xk, w0.y, o[1]);
        o[2] = fmaf(xk, w0.z, o[2]);  o[3] = fmaf(xk, w0.w, o[3]);
        o[4] = fmaf(xk, w1.x, o[4]);  o[5] = fmaf(xk, w1.y, o[5]);
        o[6] = fmaf(xk, w1.z, o[6]);  o[7] = fmaf(xk, w1.w, o[7]);
        o[8] = fmaf(xk, w2.x, o[8]);  o[9] = fmaf(xk, w2.y, o[9]);
        o[10] = fmaf(xk, w2.z, o[10]); o[11] = fmaf(xk, w2.w, o[11]);
        o[12] = fmaf(xk, w3.x, o[12]); o[13] = fmaf(xk, w3.y, o[13]);
        o[14] = fmaf(xk, w3.z, o[14]); o[15] = fmaf(xk, w3.w, o[15]);
    }
    uint4 p0, p1;
    p0.x = pkh(dv * fmaxf(o[0], 0.f),  dv * fmaxf(o[1], 0.f));
    p0.y = pkh(dv * fmaxf(o[2], 0.f),  dv * fmaxf(o[3], 0.f));
    p0.z = pkh(dv * fmaxf(o[4], 0.f),  dv * fmaxf(o[5], 0.f));
    p0.w = pkh(dv * fmaxf(o[6], 0.f),  dv * fmaxf(o[7], 0.f));
    p1.x = pkh(dv * fmaxf(o[8], 0.f),  dv * fmaxf(o[9], 0.f));
    p1.y = pkh(dv * fmaxf(o[10], 0.f), dv * fmaxf(o[11], 0.f));
    p1.z = pkh(dv * fmaxf(o[12], 0.f), dv * fmaxf(o[13], 0.f));
    p1.w = pkh(dv * fmaxf(o[14], 0.f), dv * fmaxf(o[15], 0.f));
    uint4* out4 = (uint4*)y2b;
    out4[(size_t)pv * 4 + c * 2]     = p0;
    out4[(size_t)pv * 4 + c * 2 + 1] = p1;
}

// ---- agg(32-dim, fp16 rows) -> fp16 a3 in RANK order -----------------------
// 4 lanes/node; gather via perm/offp; sequential a3p write (t3fc reads ranks).
__global__ void __launch_bounds__(256)
agg3_kernel(const unsigned int* __restrict__ y2b, const uint2* __restrict__ offp,
            const int* __restrict__ adj, const float* __restrict__ dinvp,
            const int* __restrict__ perm,
            _Float16* __restrict__ a3out, int n) {
    int t = blockIdx.x * 256 + threadIdx.x;
    int r = t >> 2, c = t & 3;
    if (r >= n) return;
    const int pv = perm[r];
    const uint2 oo = offp[r];
    const uint4* yb = (const uint4*)y2b;
    uint4 us = yb[(size_t)pv * 4 + c];   // self
    float a0 = h_lo(us.x), a1 = h_hi(us.x), a2 = h_lo(us.y), a3 = h_hi(us.y),
          a4 = h_lo(us.z), a5 = h_hi(us.z), a6 = h_lo(us.w), a7 = h_hi(us.w);
    float c0 = 0, c1 = 0, c2 = 0, c3 = 0, c4 = 0, c5 = 0, c6 = 0, c7 = 0;
    int beg = (int)oo.x, end = (int)oo.y;
    int e = beg;
    for (; e + 4 <= end; e += 4) {
        int s0 = adj[e], s1 = adj[e + 1], s2 = adj[e + 2], s3 = adj[e + 3];
        uint4 u0 = yb[(size_t)s0 * 4 + c];
        uint4 u1 = yb[(size_t)s1 * 4 + c];
        uint4 u2 = yb[(size_t)s2 * 4 + c];
        uint4 u3 = yb[(size_t)s3 * 4 + c];
        UNPK8_ADD(a, u0) UNPK8_ADD(c, u1) UNPK8_ADD(a, u2) UNPK8_ADD(c, u3)
    }
    for (; e + 2 <= end; e += 2) {
        int s0 = adj[e], s1 = adj[e + 1];
        uint4 u0 = yb[(size_t)s0 * 4 + c];
        uint4 u1 = yb[(size_t)s1 * 4 + c];
        UNPK8_ADD(a, u0) UNPK8_ADD(c, u1)
    }
    if (e < end) {
        uint4 u0 = yb[(size_t)adj[e] * 4 + c];
        UNPK8_ADD(a, u0)
    }
    float dv = dinvp[r];
    uint4 st;
    st.x = pkh((a0 + c0) * dv, (a1 + c1) * dv);
    st.y = pkh((a2 + c2) * dv, (a3 + c3) * dv);
    st.z = pkh((a4 + c4) * dv, (a5 + c5) * dv);
    st.w = pkh((a6 + c6) * dv, (a7 + c7) * dv);
    ((uint4*)a3out)[(size_t)r * 4 + c] = st;   // rank order, sequential
}

// ---- Fused layer-3 transform + FC via MFMA (rank in, perm-scattered out) ---
__global__ void __launch_bounds__(256)
t3fc_kernel(const _Float16* __restrict__ a3h, const int* __restrict__ perm,
            const _Float16* __restrict__ w3f, const float* __restrict__ b3,
            const _Float16* __restrict__ wff, const float* __restrict__ bf,
            float* __restrict__ out) {
    __shared__ __align__(16) _Float16 tA[4][1024];   // [wave][ks*512 + row*32 + h*8 + e]
    const int tid = threadIdx.x;
    const int w = tid >> 6, l = tid & 63;
    const int lr = l & 15, lh = l >> 4;
    const int vbase = blockIdx.x * 64 + w * 16;      // rank space
    const int fragoff = lr * 32 + lh * 8;

    // A1: rank row = vbase+lr, k = lh*8..lh*8+7 (fp16, 16B/lane)
    half8 A1 = *(const half8*)(a3h + (size_t)(vbase + lr) * 32 + lh * 8);

    // GEMM1: 4 col-tiles, K=32 in one MFMA each
    float4v c1[4];
#pragma unroll
    for (int nt = 0; nt < 4; nt++) {
        float bv = b3[nt * 16 + lr];                  // D col = nt*16+lr
        float4v ci = {bv, bv, bv, bv};
        half8 B = *(const half8*)(w3f + nt * 512 + fragoff);
        c1[nt] = __builtin_amdgcn_mfma_f32_16x16x32_f16(A1, B, ci, 0, 0, 0);
    }

    // relu -> fp16 -> per-wave frag-ordered scratch.
    _Float16* tw = tA[w];
#pragma unroll
    for (int nt = 0; nt < 4; nt++) {
        int k2 = nt * 16 + lr;
        int base = (k2 >> 5) * 512 + ((k2 >> 3) & 3) * 8 + (k2 & 7);
#pragma unroll
        for (int rr = 0; rr < 4; rr++)
            tw[base + (lh * 4 + rr) * 32] = (_Float16)fmaxf(c1[nt][rr], 0.f);
    }

    // GEMM2: K=64 = 2 k-steps x 4 col-tiles
    float4v c2[4];
#pragma unroll
    for (int nt = 0; nt < 4; nt++) {
        float bv = bf[nt * 16 + lr];
        c2[nt] = (float4v){bv, bv, bv, bv};
    }
#pragma unroll
    for (int ks = 0; ks < 2; ks++) {
        half8 A2 = *(const half8*)(tw + ks * 512 + fragoff);
#pragma unroll
        for (int nt = 0; nt < 4; nt++) {
            half8 B = *(const half8*)(wff + (ks * 4 + nt) * 512 + fragoff);
            c2[nt] = __builtin_amdgcn_mfma_f32_16x16x32_f16(A2, B, c2[nt], 0, 0, 0);
        }
    }

    // store: D elem (rank row = lh*4+rr, col = nt*16+lr) -> node perm[row]
    int pr[4];
#pragma unroll
    for (int rr = 0; rr < 4; rr++) pr[rr] = perm[vbase + lh * 4 + rr];
#pragma unroll
    for (int nt = 0; nt < 4; nt++) {
#pragma unroll
        for (int rr = 0; rr < 4; rr++)
            out[(size_t)pr[rr] * 64 + nt * 16 + lr] = c2[nt][rr];
    }
}

extern "C" void kernel_launch(void* const* d_in, const int* in_sizes, int n_in,
                              void* d_out, int out_size, void* d_ws, size_t ws_size,
                              hipStream_t stream) {
    const float* x  = (const float*)d_in[0];
    const float* W1 = (const float*)d_in[1];
    const float* b1 = (const float*)d_in[2];
    const float* W2 = (const float*)d_in[3];
    const float* b2 = (const float*)d_in[4];
    const float* W3 = (const float*)d_in[5];
    const float* b3 = (const float*)d_in[6];
    const float* Wf = (const float*)d_in[7];
    const float* bf = (const float*)d_in[8];
    const int*   ei = (const int*)d_in[9];

    const int N = in_sizes[0] / 8;   // 262144
    const int E = in_sizes[9] / 2;   // 2097152
    const int* srcv = ei;
    const int* dstv = ei + E;
    const int shift = 10;            // log2(NPB)

    // Workspace layout (64B-aligned chunks)
    char* p = (char*)d_ws;
    auto take = [&p](size_t bytes) { char* q = p; p += (bytes + 63) & ~size_t(63); return q; };
    int*   off   = (int*)take((size_t)(N + 16) * 4);
    float* dinv  = (float*)take((size_t)N * 4);
    int*   adj   = (int*)take((size_t)E * 4);
    int*   ghist = (int*)take(NB * 4);
    int*   bbase = (int*)take((NB + 1) * 4);
    int*   gcur  = (int*)take(NB * 4);
    int*   dhist = (int*)take(DB * 4);
    int*   dcur  = (int*)take(DB * 4);
    int*   perm  = (int*)take((size_t)N * 4);
    uint2* offp  = (uint2*)take((size_t)N * 8);
    float* dinvp = (float*)take((size_t)N * 4);
    _Float16* w3f = (_Float16*)take(32 * 64 * 2);      // frag-ordered fp16 W3
    _Float16* wff = (_Float16*)take(64 * 64 * 2);      // frag-ordered fp16 Wf
    char*  bufA  = take((size_t)N * 32 * 4);           // y0h (4MB) then a3h (fp16, 16MB)
    char*  bufB  = take((size_t)N * 16 * 4);           // y1h (fp16, 8MB)
    char*  regX  = take((size_t)N * 32 * 2);           // 16MB: bedge (8MB) then y2b (fp16)
    unsigned int* bedge = (unsigned int*)regX;
    unsigned int* y2b   = (unsigned int*)regX;
    _Float16* y0h = (_Float16*)bufA;
    _Float16* a3h = (_Float16*)bufA;
    _Float16* y1h = (_Float16*)bufB;

    hipMemsetAsync(ghist, 0, NB * 4, stream);

    int nt = (E + TILE - 1) / TILE;  // 512 tiles
    hist_kernel<<<nt, 256, 0, stream>>>(dstv, ghist, E, shift);
    bscan_kernel<<<1, NB, 0, stream>>>(ghist, bbase, gcur, dhist, W3, Wf, w3f, wff);
    partition_kernel<<<nt, 256, 0, stream>>>(srcv, dstv, gcur, bedge, E, shift, NPB - 1);
    build_kernel<<<NB, 256, 0, stream>>>(bbase, bedge, x, off, dinv, adj, y0h, dhist);
    dscan_kernel<<<1, DB, 0, stream>>>(dhist, dcur);
    dscatter_kernel<<<N / 1024, 256, 0, stream>>>(off, dinv, dcur, perm, offp, dinvp);

    // L1: agg(y0h) + transform 8->16 -> y1h (fp16), degree-sorted
    aggt1_kernel<<<N / 256, 256, 0, stream>>>(y0h, offp, adj, dinvp, perm, W1, b1, y1h);
    // L2: agg(y1h) + transform 16->32 -> y2b (fp16), degree-sorted
    aggt2_kernel<<<N / 128, 256, 0, stream>>>(y1h, offp, adj, dinvp, perm, W2, b2, y2b);
    // L3: agg(y2b) -> a3h rank-ordered, then MFMA transform+FC -> out (perm scatter)
    agg3_kernel<<<(N * 4) / 256, 256, 0, stream>>>(y2b, offp, adj, dinvp, perm, a3h, N);
    t3fc_kernel<<<N / 64, 256, 0, stream>>>(a3h, perm, w3f, b3, wff, bf, (float*)d_out);
}

// Round 8
// 300.362 us; speedup vs baseline: 1.0649x; 1.0649x over previous
//
#include <hip/hip_runtime.h>
#include <hip/hip_bf16.h>

// GCN x3 + FC on a fixed random graph.
//   1. Bucket-partition CSR build: hist -> scan -> packed partition
//      (src|dl<<18) -> per-bucket build (LDS atomics, coalesced I/O) with
//      fused prescale y0 = dinv*x (fp16).
//   2. Pull aggregation over pre-scaled features y = dinv*h:
//      out[v] = dinv[v]*(sum y[s] + y[v]).  All inter-layer features fp16.
//   3. R15: DIM-SPLIT aggregation passes.  R13/R14 showed aggs are bound by
//      random-sector fetch volume = f(table footprint vs 4MB per-XCD L2):
//      y1 8MB -> 45% hit -> 74MB gather fetch (aggt2).  R14's degree sort
//      REGRESSED (+36MB from scattered self-IO): scheduling isn't the lever,
//      footprint is.  Now y1 is stored as two 4MB planes (dims 0-7 / 8-15);
//      aggt2 runs as two sequential kernels, each gathering one L2-resident
//      plane; fp32 partial (8MB, NT) bridges them.  Streaming accesses (adj,
//      partials, plane writes) are non-temporal so they don't evict table
//      lines.  aggt1's table (y0h 4MB) already fits -> NT hints only.
//   4. t3fc (R10): MFMA mfma_f32_16x16x32_f16; weights pre-converted to
//      B-frag-ordered fp16 in bscan; per-wave 2KB LDS relu scratch.

#define NB   256     // dst buckets
#define NPB  1024    // nodes per bucket (N = NB*NPB)
#define TILE 4096    // edges per partition tile
#define SRCMASK 0x3FFFFu

typedef _Float16 half8 __attribute__((ext_vector_type(8)));
typedef float float4v __attribute__((ext_vector_type(4)));
typedef unsigned int u32x4 __attribute__((ext_vector_type(4)));

__device__ __forceinline__ unsigned pkh(float a, float b) {  // 2x fp32 -> packed fp16 (RNE)
    unsigned short ua = __builtin_bit_cast(unsigned short, (_Float16)a);
    unsigned short ub = __builtin_bit_cast(unsigned short, (_Float16)b);
    return (unsigned)ua | ((unsigned)ub << 16);
}
__device__ __forceinline__ float h_lo(unsigned u) {
    return (float)__builtin_bit_cast(_Float16, (unsigned short)(u & 0xFFFFu));
}
__device__ __forceinline__ float h_hi(unsigned u) {
    return (float)__builtin_bit_cast(_Float16, (unsigned short)(u >> 16));
}
__device__ __forceinline__ int ld_nt(const int* p) { return __builtin_nontemporal_load(p); }

#define UNPK8_ADD(A, u) \
    A##0 += h_lo(u.x); A##1 += h_hi(u.x); A##2 += h_lo(u.y); A##3 += h_hi(u.y); \
    A##4 += h_lo(u.z); A##5 += h_hi(u.z); A##6 += h_lo(u.w); A##7 += h_hi(u.w);

// ---- P1: global bucket histogram -------------------------------------------
__global__ void hist_kernel(const int* __restrict__ dst, int* __restrict__ ghist,
                            int E, int shift) {
    __shared__ int h[NB];
    int tid = threadIdx.x;
    h[tid] = 0;
    __syncthreads();
    int base = blockIdx.x * TILE;
    int cnt = min(TILE, E - base);
    for (int i = tid; i < cnt; i += 256)
        atomicAdd(&h[dst[base + i] >> shift], 1);
    __syncthreads();
    int v = h[tid];
    if (v) atomicAdd(&ghist[tid], v);
}

// ---- P2: scan bucket counts + weight->fp16 frag conversion -----------------
// Frag order for B of mfma_f32_16x16x32_f16: dest[( (k>>5)*4 + (j>>4) )*512
//  + (j&15)*32 + ((k>>3)&3)*8 + (k&7)]  (j = col, k = row of W[k][j]).
__global__ void bscan_kernel(const int* __restrict__ ghist, int* __restrict__ bbase,
                             int* __restrict__ gcursor,
                             const float* __restrict__ W3, const float* __restrict__ Wf,
                             _Float16* __restrict__ w3f, _Float16* __restrict__ wff) {
    __shared__ int sh[NB];
    int tid = threadIdx.x;
    int v = ghist[tid];
    sh[tid] = v;
    __syncthreads();
    for (int o = 1; o < NB; o <<= 1) {
        int t = (tid >= o) ? sh[tid - o] : 0;
        __syncthreads();
        sh[tid] += t;
        __syncthreads();
    }
    int incl = sh[tid];
    bbase[tid] = incl - v;
    gcursor[tid] = incl - v;
    if (tid == NB - 1) bbase[NB] = incl;
    // W3: [32][64]
    for (int i = tid; i < 32 * 64; i += NB) {
        int k = i >> 6, j = i & 63;
        w3f[(j >> 4) * 512 + (j & 15) * 32 + (k >> 3) * 8 + (k & 7)] = (_Float16)W3[i];
    }
    // Wf: [64][64]
    for (int i = tid; i < 64 * 64; i += NB) {
        int k = i >> 6, j = i & 63;
        wff[((k >> 5) * 4 + (j >> 4)) * 512 + (j & 15) * 32 + ((k >> 3) & 3) * 8 + (k & 7)]
            = (_Float16)Wf[i];
    }
}

// ---- P3: partition edges into bucket-contiguous packed stream --------------
__global__ void __launch_bounds__(256)
partition_kernel(const int* __restrict__ src, const int* __restrict__ dst,
                 int* __restrict__ gcursor, unsigned int* __restrict__ bedge,
                 int E, int shift, int mask) {
    __shared__ int h[NB], st[NB], gp[NB];
    __shared__ unsigned short rk[TILE];
    __shared__ int sd[TILE];
    __shared__ int ss[TILE];
    int tid = threadIdx.x;
    h[tid] = 0;
    __syncthreads();
    int base = blockIdx.x * TILE;
    int cnt = min(TILE, E - base);
    for (int i = tid; i < cnt; i += 256)
        rk[i] = (unsigned short)atomicAdd(&h[dst[base + i] >> shift], 1);
    __syncthreads();
    int hv = h[tid];
    st[tid] = hv;
    __syncthreads();
    for (int o = 1; o < NB; o <<= 1) {
        int t = (tid >= o) ? st[tid - o] : 0;
        __syncthreads();
        st[tid] += t;
        __syncthreads();
    }
    st[tid] -= hv;
    gp[tid] = hv ? atomicAdd(&gcursor[tid], hv) : 0;
    __syncthreads();
    for (int i = tid; i < cnt; i += 256) {
        int d = dst[base + i];
        int b = d >> shift;
        int pos = st[b] + rk[i];
        sd[pos] = d;
        ss[pos] = src[base + i];
    }
    __syncthreads();
    for (int i = tid; i < cnt; i += 256) {
        int d = sd[i];
        int b = d >> shift;
        int g = gp[b] + (i - st[b]);
        bedge[g] = (unsigned int)ss[i] | ((unsigned int)(d & mask) << 18);
    }
}

// ---- P4: per-bucket CSR build + fused prescale (fp16 y0) -------------------
__global__ void __launch_bounds__(256)
build_kernel(const int* __restrict__ bbase, const unsigned int* __restrict__ bedge,
             const float* __restrict__ x,
             int* __restrict__ off, float* __restrict__ dinv, int* __restrict__ adj,
             _Float16* __restrict__ y0h) {
    __shared__ int deg1[NPB];
    __shared__ int cur[NPB];
    __shared__ int bs[256];
    int tid = threadIdx.x;
    int b = blockIdx.x;
    int s = bbase[b], e = bbase[b + 1];
    int base = tid * 4;
#pragma unroll
    for (int i = 0; i < 4; i++) deg1[base + i] = 0;
    __syncthreads();
    for (int i = s + tid; i < e; i += 256)
        atomicAdd(&deg1[bedge[i] >> 18], 1);
    __syncthreads();
    int d0 = deg1[base], d1 = deg1[base + 1], d2 = deg1[base + 2], d3 = deg1[base + 3];
    int th = d0 + d1 + d2 + d3;
    bs[tid] = th;
    __syncthreads();
    for (int o = 1; o < 256; o <<= 1) {
        int t = (tid >= o) ? bs[tid - o] : 0;
        __syncthreads();
        bs[tid] += t;
        __syncthreads();
    }
    int run = s + bs[tid] - th;
    int vb = b * NPB + base;
    off[vb]     = run; cur[base]     = run; dinv[vb]     = rsqrtf((float)(d0 + 1)); run += d0;
    off[vb + 1] = run; cur[base + 1] = run; dinv[vb + 1] = rsqrtf((float)(d1 + 1)); run += d1;
    off[vb + 2] = run; cur[base + 2] = run; dinv[vb + 2] = rsqrtf((float)(d2 + 1)); run += d2;
    off[vb + 3] = run; cur[base + 3] = run; dinv[vb + 3] = rsqrtf((float)(d3 + 1)); run += d3;
    if (b == NB - 1 && tid == 255) off[NB * NPB] = e;   // sentinel off[N] = E
    __syncthreads();
    for (int i = s + tid; i < e; i += 256) {
        unsigned int pk = bedge[i];
        int p = atomicAdd(&cur[pk >> 18], 1);
        adj[p] = (int)(pk & SRCMASK);
    }
    // fused prescale: y0h[v] = fp16(dinv[v] * x[v])  (bucket rows, coalesced)
    for (int i = tid; i < NPB; i += 256) {
        float dv = rsqrtf((float)(deg1[i] + 1));
        const float4* xr = (const float4*)x + (size_t)(b * NPB + i) * 2;
        float4 t0 = xr[0], t1 = xr[1];
        uint4 pk;
        pk.x = pkh(t0.x * dv, t0.y * dv); pk.y = pkh(t0.z * dv, t0.w * dv);
        pk.z = pkh(t1.x * dv, t1.y * dv); pk.w = pkh(t1.z * dv, t1.w * dv);
        ((uint4*)y0h)[(size_t)b * NPB + i] = pk;
    }
}

// ---- Fused agg(8-dim fp16) + transform 8->16 -> fp16 planes y1a/y1b --------
// 1 lane/node, full 16B row per gather (y0h table = 4MB, L2-resident);
// adj via NT loads, plane writes NT.  Transform fully in registers.
__global__ void __launch_bounds__(256)
aggt1_kernel(const _Float16* __restrict__ y0h, const int* __restrict__ off,
             const int* __restrict__ adj, const float* __restrict__ dinv,
             const float* __restrict__ W1, const float* __restrict__ b1,
             _Float16* __restrict__ y1a, _Float16* __restrict__ y1b) {
    __shared__ float Ws[8 * 16];
    __shared__ float bsh[16];
    const int tid = threadIdx.x;
    if (tid < 128) Ws[tid] = W1[tid];
    if (tid < 16) bsh[tid] = b1[tid];
    const int vg = blockIdx.x * 256 + tid;
    const u32x4* y4 = (const u32x4*)y0h;
    int beg = off[vg], end = off[vg + 1];
    u32x4 us = y4[vg];   // self (full row)
    float a0 = h_lo(us.x), a1 = h_hi(us.x), a2 = h_lo(us.y), a3 = h_hi(us.y),
          a4 = h_lo(us.z), a5 = h_hi(us.z), a6 = h_lo(us.w), a7 = h_hi(us.w);
    float c0 = 0, c1 = 0, c2 = 0, c3 = 0, c4 = 0, c5 = 0, c6 = 0, c7 = 0;
    int e = beg;
    for (; e + 8 <= end; e += 8) {
        int s0 = ld_nt(adj + e),     s1 = ld_nt(adj + e + 1);
        int s2 = ld_nt(adj + e + 2), s3 = ld_nt(adj + e + 3);
        int s4 = ld_nt(adj + e + 4), s5 = ld_nt(adj + e + 5);
        int s6 = ld_nt(adj + e + 6), s7 = ld_nt(adj + e + 7);
        u32x4 u0 = y4[s0], u1 = y4[s1], u2 = y4[s2], u3 = y4[s3];
        u32x4 u4 = y4[s4], u5 = y4[s5], u6 = y4[s6], u7 = y4[s7];
        UNPK8_ADD(a, u0) UNPK8_ADD(c, u1) UNPK8_ADD(a, u2) UNPK8_ADD(c, u3)
        UNPK8_ADD(a, u4) UNPK8_ADD(c, u5) UNPK8_ADD(a, u6) UNPK8_ADD(c, u7)
    }
    for (; e + 2 <= end; e += 2) {
        int s0 = ld_nt(adj + e), s1 = ld_nt(adj + e + 1);
        u32x4 u0 = y4[s0], u1 = y4[s1];
        UNPK8_ADD(a, u0) UNPK8_ADD(c, u1)
    }
    if (e < end) {
        u32x4 u0 = y4[ld_nt(adj + e)];
        UNPK8_ADD(a, u0)
    }
    float dv = dinv[vg];
    float in[8];
    in[0] = (a0 + c0) * dv; in[1] = (a1 + c1) * dv;
    in[2] = (a2 + c2) * dv; in[3] = (a3 + c3) * dv;
    in[4] = (a4 + c4) * dv; in[5] = (a5 + c5) * dv;
    in[6] = (a6 + c6) * dv; in[7] = (a7 + c7) * dv;
    __syncthreads();   // Ws/bsh visibility
    const float4* W4 = (const float4*)Ws;
    float o[16];
    {
        float4 b0 = ((const float4*)bsh)[0], b1v = ((const float4*)bsh)[1];
        float4 b2v = ((const float4*)bsh)[2], b3v = ((const float4*)bsh)[3];
        o[0] = b0.x; o[1] = b0.y; o[2] = b0.z; o[3] = b0.w;
        o[4] = b1v.x; o[5] = b1v.y; o[6] = b1v.z; o[7] = b1v.w;
        o[8] = b2v.x; o[9] = b2v.y; o[10] = b2v.z; o[11] = b2v.w;
        o[12] = b3v.x; o[13] = b3v.y; o[14] = b3v.z; o[15] = b3v.w;
    }
#pragma unroll
    for (int k = 0; k < 8; k++) {
        float xk = in[k];
        float4 w0 = W4[k * 4 + 0], w1 = W4[k * 4 + 1];
        float4 w2 = W4[k * 4 + 2], w3 = W4[k * 4 + 3];
        o[0] = fmaf(xk, w0.x, o[0]);  o[1] = fmaf(xk, w0.y, o[1]);
        o[2] = fmaf(xk, w0.z, o[2]);  o[3] = fmaf(xk, w0.w, o[3]);
        o[4] = fmaf(xk, w1.x, o[4]);  o[5] = fmaf(xk, w1.y, o[5]);
        o[6] = fmaf(xk, w1.z, o[6]);  o[7] = fmaf(xk, w1.w, o[7]);
        o[8] = fmaf(xk, w2.x, o[8]);  o[9] = fmaf(xk, w2.y, o[9]);
        o[10] = fmaf(xk, w2.z, o[10]); o[11] = fmaf(xk, w2.w, o[11]);
        o[12] = fmaf(xk, w3.x, o[12]); o[13] = fmaf(xk, w3.y, o[13]);
        o[14] = fmaf(xk, w3.z, o[14]); o[15] = fmaf(xk, w3.w, o[15]);
    }
    u32x4 p0, p1;
    p0.x = pkh(dv * fmaxf(o[0], 0.f),  dv * fmaxf(o[1], 0.f));
    p0.y = pkh(dv * fmaxf(o[2], 0.f),  dv * fmaxf(o[3], 0.f));
    p0.z = pkh(dv * fmaxf(o[4], 0.f),  dv * fmaxf(o[5], 0.f));
    p0.w = pkh(dv * fmaxf(o[6], 0.f),  dv * fmaxf(o[7], 0.f));
    p1.x = pkh(dv * fmaxf(o[8], 0.f),  dv * fmaxf(o[9], 0.f));
    p1.y = pkh(dv * fmaxf(o[10], 0.f), dv * fmaxf(o[11], 0.f));
    p1.z = pkh(dv * fmaxf(o[12], 0.f), dv * fmaxf(o[13], 0.f));
    p1.w = pkh(dv * fmaxf(o[14], 0.f), dv * fmaxf(o[15], 0.f));
    __builtin_nontemporal_store(p0, (u32x4*)y1a + vg);   // plane A: dims 0-7
    __builtin_nontemporal_store(p1, (u32x4*)y1b + vg);   // plane B: dims 8-15
}

// ---- aggt2 pass A: gather-sum plane A (4MB, L2-resident) -> fp32 partial ---
// 1 lane/node; raw sums (no dinv); partial written NT (streaming).
__global__ void __launch_bounds__(256)
aggt2a_kernel(const _Float16* __restrict__ y1a, const int* __restrict__ off,
              const int* __restrict__ adj, float* __restrict__ P) {
    const int vg = blockIdx.x * 256 + threadIdx.x;
    const u32x4* y4 = (const u32x4*)y1a;
    int beg = off[vg], end = off[vg + 1];
    u32x4 us = y4[vg];   // self
    float a0 = h_lo(us.x), a1 = h_hi(us.x), a2 = h_lo(us.y), a3 = h_hi(us.y),
          a4 = h_lo(us.z), a5 = h_hi(us.z), a6 = h_lo(us.w), a7 = h_hi(us.w);
    float c0 = 0, c1 = 0, c2 = 0, c3 = 0, c4 = 0, c5 = 0, c6 = 0, c7 = 0;
    int e = beg;
    for (; e + 8 <= end; e += 8) {
        int s0 = ld_nt(adj + e),     s1 = ld_nt(adj + e + 1);
        int s2 = ld_nt(adj + e + 2), s3 = ld_nt(adj + e + 3);
        int s4 = ld_nt(adj + e + 4), s5 = ld_nt(adj + e + 5);
        int s6 = ld_nt(adj + e + 6), s7 = ld_nt(adj + e + 7);
        u32x4 u0 = y4[s0], u1 = y4[s1], u2 = y4[s2], u3 = y4[s3];
        u32x4 u4 = y4[s4], u5 = y4[s5], u6 = y4[s6], u7 = y4[s7];
        UNPK8_ADD(a, u0) UNPK8_ADD(c, u1) UNPK8_ADD(a, u2) UNPK8_ADD(c, u3)
        UNPK8_ADD(a, u4) UNPK8_ADD(c, u5) UNPK8_ADD(a, u6) UNPK8_ADD(c, u7)
    }
    for (; e + 2 <= end; e += 2) {
        int s0 = ld_nt(adj + e), s1 = ld_nt(adj + e + 1);
        u32x4 u0 = y4[s0], u1 = y4[s1];
        UNPK8_ADD(a, u0) UNPK8_ADD(c, u1)
    }
    if (e < end) {
        u32x4 u0 = y4[ld_nt(adj + e)];
        UNPK8_ADD(a, u0)
    }
    float4v q0 = {a0 + c0, a1 + c1, a2 + c2, a3 + c3};
    float4v q1 = {a4 + c4, a5 + c5, a6 + c6, a7 + c7};
    __builtin_nontemporal_store(q0, (float4v*)(P + (size_t)vg * 8));
    __builtin_nontemporal_store(q1, (float4v*)(P + (size_t)vg * 8) + 1);
}

// ---- aggt2 pass B: gather-sum plane B + partial -> transform 16->32 -> y2b -
// 1 lane/node; plane B is the only gather table (4MB, L2-resident).
__global__ void __launch_bounds__(256)
aggt2b_kernel(const _Float16* __restrict__ y1b, const int* __restrict__ off,
              const int* __restrict__ adj, const float* __restrict__ dinv,
              const float* __restrict__ P,
              const float* __restrict__ W2, const float* __restrict__ b2,
              unsigned int* __restrict__ y2b) {
    __shared__ float Ws[16 * 32];
    __shared__ float bsh[32];
    const int tid = threadIdx.x;
    for (int i = tid; i < 16 * 32; i += 256) Ws[i] = W2[i];
    if (tid < 32) bsh[tid] = b2[tid];
    const int vg = blockIdx.x * 256 + tid;
    const u32x4* y4 = (const u32x4*)y1b;
    int beg = off[vg], end = off[vg + 1];
    u32x4 us = y4[vg];   // self
    float a0 = h_lo(us.x), a1 = h_hi(us.x), a2 = h_lo(us.y), a3 = h_hi(us.y),
          a4 = h_lo(us.z), a5 = h_hi(us.z), a6 = h_lo(us.w), a7 = h_hi(us.w);
    float c0 = 0, c1 = 0, c2 = 0, c3 = 0, c4 = 0, c5 = 0, c6 = 0, c7 = 0;
    int e = beg;
    for (; e + 8 <= end; e += 8) {
        int s0 = ld_nt(adj + e),     s1 = ld_nt(adj + e + 1);
        int s2 = ld_nt(adj + e + 2), s3 = ld_nt(adj + e + 3);
        int s4 = ld_nt(adj + e + 4), s5 = ld_nt(adj + e + 5);
        int s6 = ld_nt(adj + e + 6), s7 = ld_nt(adj + e + 7);
        u32x4 u0 = y4[s0], u1 = y4[s1], u2 = y4[s2], u3 = y4[s3];
        u32x4 u4 = y4[s4], u5 = y4[s5], u6 = y4[s6], u7 = y4[s7];
        UNPK8_ADD(a, u0) UNPK8_ADD(c, u1) UNPK8_ADD(a, u2) UNPK8_ADD(c, u3)
        UNPK8_ADD(a, u4) UNPK8_ADD(c, u5) UNPK8_ADD(a, u6) UNPK8_ADD(c, u7)
    }
    for (; e + 2 <= end; e += 2) {
        int s0 = ld_nt(adj + e), s1 = ld_nt(adj + e + 1);
        u32x4 u0 = y4[s0], u1 = y4[s1];
        UNPK8_ADD(a, u0) UNPK8_ADD(c, u1)
    }
    if (e < end) {
        u32x4 u0 = y4[ld_nt(adj + e)];
        UNPK8_ADD(a, u0)
    }
    float dv = dinv[vg];
    float4v q0 = __builtin_nontemporal_load((const float4v*)(P + (size_t)vg * 8));
    float4v q1 = __builtin_nontemporal_load((const float4v*)(P + (size_t)vg * 8) + 1);
    float in[16];
    in[0] = q0.x * dv; in[1] = q0.y * dv; in[2] = q0.z * dv; in[3] = q0.w * dv;
    in[4] = q1.x * dv; in[5] = q1.y * dv; in[6] = q1.z * dv; in[7] = q1.w * dv;
    in[8]  = (a0 + c0) * dv; in[9]  = (a1 + c1) * dv;
    in[10] = (a2 + c2) * dv; in[11] = (a3 + c3) * dv;
    in[12] = (a4 + c4) * dv; in[13] = (a5 + c5) * dv;
    in[14] = (a6 + c6) * dv; in[15] = (a7 + c7) * dv;
    __syncthreads();   // Ws/bsh visibility
    const float4* W4 = (const float4*)Ws;   // 8 float4 per k-row
    float o[32];
#pragma unroll
    for (int jj = 0; jj < 32; jj += 4) {
        float4 bv = *(const float4*)&bsh[jj];
        o[jj] = bv.x; o[jj + 1] = bv.y; o[jj + 2] = bv.z; o[jj + 3] = bv.w;
    }
#pragma unroll
    for (int k = 0; k < 16; k++) {
        float xk = in[k];
#pragma unroll
        for (int q = 0; q < 8; q++) {
            float4 w = W4[k * 8 + q];
            o[q * 4 + 0] = fmaf(xk, w.x, o[q * 4 + 0]);
            o[q * 4 + 1] = fmaf(xk, w.y, o[q * 4 + 1]);
            o[q * 4 + 2] = fmaf(xk, w.z, o[q * 4 + 2]);
            o[q * 4 + 3] = fmaf(xk, w.w, o[q * 4 + 3]);
        }
    }
    u32x4* out4 = (u32x4*)y2b + (size_t)vg * 4;
#pragma unroll
    for (int q = 0; q < 4; q++) {
        u32x4 pk;
        pk.x = pkh(dv * fmaxf(o[q * 8 + 0], 0.f), dv * fmaxf(o[q * 8 + 1], 0.f));
        pk.y = pkh(dv * fmaxf(o[q * 8 + 2], 0.f), dv * fmaxf(o[q * 8 + 3], 0.f));
        pk.z = pkh(dv * fmaxf(o[q * 8 + 4], 0.f), dv * fmaxf(o[q * 8 + 5], 0.f));
        pk.w = pkh(dv * fmaxf(o[q * 8 + 6], 0.f), dv * fmaxf(o[q * 8 + 7], 0.f));
        __builtin_nontemporal_store(pk, out4 + q);
    }
}

// ---- agg(32-dim, fp16 rows) -> fp16 a3 -------------------------------------
// 4 lanes/node, each lane one 16B (8 fp16) chunk; 4-wide unroll; NT adj.
__global__ void __launch_bounds__(256)
agg3_kernel(const unsigned int* __restrict__ y2b, const int* __restrict__ off,
            const int* __restrict__ adj, const float* __restrict__ dinv,
            _Float16* __restrict__ a3out, int n) {
    int t = blockIdx.x * 256 + threadIdx.x;
    int v = t >> 2, c = t & 3;
    if (v >= n) return;
    const u32x4* yb = (const u32x4*)y2b;
    u32x4 us = yb[(size_t)v * 4 + c];   // self
    float a0 = h_lo(us.x), a1 = h_hi(us.x), a2 = h_lo(us.y), a3 = h_hi(us.y),
          a4 = h_lo(us.z), a5 = h_hi(us.z), a6 = h_lo(us.w), a7 = h_hi(us.w);
    float c0 = 0, c1 = 0, c2 = 0, c3 = 0, c4 = 0, c5 = 0, c6 = 0, c7 = 0;
    int beg = off[v], end = off[v + 1];
    int e = beg;
    for (; e + 4 <= end; e += 4) {
        int s0 = ld_nt(adj + e),     s1 = ld_nt(adj + e + 1);
        int s2 = ld_nt(adj + e + 2), s3 = ld_nt(adj + e + 3);
        u32x4 u0 = yb[(size_t)s0 * 4 + c];
        u32x4 u1 = yb[(size_t)s1 * 4 + c];
        u32x4 u2 = yb[(size_t)s2 * 4 + c];
        u32x4 u3 = yb[(size_t)s3 * 4 + c];
        UNPK8_ADD(a, u0) UNPK8_ADD(c, u1) UNPK8_ADD(a, u2) UNPK8_ADD(c, u3)
    }
    for (; e + 2 <= end; e += 2) {
        int s0 = ld_nt(adj + e), s1 = ld_nt(adj + e + 1);
        u32x4 u0 = yb[(size_t)s0 * 4 + c];
        u32x4 u1 = yb[(size_t)s1 * 4 + c];
        UNPK8_ADD(a, u0) UNPK8_ADD(c, u1)
    }
    if (e < end) {
        u32x4 u0 = yb[(size_t)ld_nt(adj + e) * 4 + c];
        UNPK8_ADD(a, u0)
    }
    float dv = dinv[v];
    u32x4 st;
    st.x = pkh((a0 + c0) * dv, (a1 + c1) * dv);
    st.y = pkh((a2 + c2) * dv, (a3 + c3) * dv);
    st.z = pkh((a4 + c4) * dv, (a5 + c5) * dv);
    st.w = pkh((a6 + c6) * dv, (a7 + c7) * dv);
    ((u32x4*)a3out)[(size_t)v * 4 + c] = st;
}

// ---- Fused layer-3 transform + FC via MFMA ---------------------------------
// 256 threads = 4 waves, 64 nodes/block (16 per wave).  No __syncthreads:
// B-frags come straight from global (frag-ordered fp16, L1-hot), the only
// LDS is a per-wave 2KB frag-ordered relu(t) scratch (contiguous 16B/lane
// reads -> conflict-free).  Intra-wave LDS dep: compiler-inserted lgkmcnt.
__global__ void __launch_bounds__(256)
t3fc_kernel(const _Float16* __restrict__ a3h,
            const _Float16* __restrict__ w3f, const float* __restrict__ b3,
            const _Float16* __restrict__ wff, const float* __restrict__ bf,
            float* __restrict__ out) {
    __shared__ __align__(16) _Float16 tA[4][1024];   // [wave][ks*512 + row*32 + h*8 + e]
    const int tid = threadIdx.x;
    const int w = tid >> 6, l = tid & 63;
    const int lr = l & 15, lh = l >> 4;
    const int vbase = blockIdx.x * 64 + w * 16;
    const int fragoff = lr * 32 + lh * 8;

    // A1: node row = vbase+lr, k = lh*8..lh*8+7 (fp16, 16B/lane)
    half8 A1 = *(const half8*)(a3h + (size_t)(vbase + lr) * 32 + lh * 8);

    // GEMM1: 4 col-tiles, K=32 in one MFMA each
    float4v c1[4];
#pragma unroll
    for (int nt = 0; nt < 4; nt++) {
        float bv = b3[nt * 16 + lr];                  // D col = nt*16+lr
        float4v ci = {bv, bv, bv, bv};
        half8 B = *(const half8*)(w3f + nt * 512 + fragoff);
        c1[nt] = __builtin_amdgcn_mfma_f32_16x16x32_f16(A1, B, ci, 0, 0, 0);
    }

    // relu -> fp16 -> per-wave frag-ordered scratch.
    // D elem (row = lh*4+r, col = nt*16+lr) becomes t[row][k2=col]:
    //   idx = (k2>>5)*512 + row*32 + ((k2>>3)&3)*8 + (k2&7)
    _Float16* tw = tA[w];
#pragma unroll
    for (int nt = 0; nt < 4; nt++) {
        int k2 = nt * 16 + lr;
        int base = (k2 >> 5) * 512 + ((k2 >> 3) & 3) * 8 + (k2 & 7);
#pragma unroll
        for (int r = 0; r < 4; r++)
            tw[base + (lh * 4 + r) * 32] = (_Float16)fmaxf(c1[nt][r], 0.f);
    }

    // GEMM2: K=64 = 2 k-steps x 4 col-tiles
    float4v c2[4];
#pragma unroll
    for (int nt = 0; nt < 4; nt++) {
        float bv = bf[nt * 16 + lr];
        c2[nt] = (float4v){bv, bv, bv, bv};
    }
#pragma unroll
    for (int ks = 0; ks < 2; ks++) {
        half8 A2 = *(const half8*)(tw + ks * 512 + fragoff);
#pragma unroll
        for (int nt = 0; nt < 4; nt++) {
            half8 B = *(const half8*)(wff + (ks * 4 + nt) * 512 + fragoff);
            c2[nt] = __builtin_amdgcn_mfma_f32_16x16x32_f16(A2, B, c2[nt], 0, 0, 0);
        }
    }

    // store: D elem (row = lh*4+r, col = nt*16+lr); 64B segments per (nt,r)
#pragma unroll
    for (int nt = 0; nt < 4; nt++) {
#pragma unroll
        for (int r = 0; r < 4; r++)
            out[(size_t)(vbase + lh * 4 + r) * 64 + nt * 16 + lr] = c2[nt][r];
    }
}

extern "C" void kernel_launch(void* const* d_in, const int* in_sizes, int n_in,
                              void* d_out, int out_size, void* d_ws, size_t ws_size,
                              hipStream_t stream) {
    const float* x  = (const float*)d_in[0];
    const float* W1 = (const float*)d_in[1];
    const float* b1 = (const float*)d_in[2];
    const float* W2 = (const float*)d_in[3];
    const float* b2 = (const float*)d_in[4];
    const float* W3 = (const float*)d_in[5];
    const float* b3 = (const float*)d_in[6];
    const float* Wf = (const float*)d_in[7];
    const float* bf = (const float*)d_in[8];
    const int*   ei = (const int*)d_in[9];

    const int N = in_sizes[0] / 8;   // 262144
    const int E = in_sizes[9] / 2;   // 2097152
    const int* srcv = ei;
    const int* dstv = ei + E;
    const int shift = 10;            // log2(NPB)

    // Workspace layout (64B-aligned chunks)
    char* p = (char*)d_ws;
    auto take = [&p](size_t bytes) { char* q = p; p += (bytes + 63) & ~size_t(63); return q; };
    int*   off   = (int*)take((size_t)(N + 16) * 4);
    float* dinv  = (float*)take((size_t)N * 4);
    int*   adj   = (int*)take((size_t)E * 4);
    int*   ghist = (int*)take(NB * 4);
    int*   bbase = (int*)take((NB + 1) * 4);
    int*   gcur  = (int*)take(NB * 4);
    _Float16* w3f = (_Float16*)take(32 * 64 * 2);      // frag-ordered fp16 W3
    _Float16* wff = (_Float16*)take(64 * 64 * 2);      // frag-ordered fp16 Wf
    char*  bufA  = take((size_t)N * 32 * 4);           // y0h (4MB) then a3h (fp16, 16MB)
    char*  bufB  = take((size_t)N * 16 * 4);           // y1a (4MB) | y1b (4MB) | P (8MB)
    char*  regX  = take((size_t)N * 32 * 2);           // 16MB: bedge (8MB) then y2b (fp16)
    unsigned int* bedge = (unsigned int*)regX;
    unsigned int* y2b   = (unsigned int*)regX;
    _Float16* y0h = (_Float16*)bufA;
    _Float16* a3h = (_Float16*)bufA;
    _Float16* y1a = (_Float16*)bufB;
    _Float16* y1b = (_Float16*)(bufB + (size_t)N * 16);
    float*    Ppart = (float*)(bufB + (size_t)N * 32);

    hipMemsetAsync(ghist, 0, NB * 4, stream);

    int nt = (E + TILE - 1) / TILE;  // 512 tiles
    hist_kernel<<<nt, 256, 0, stream>>>(dstv, ghist, E, shift);
    bscan_kernel<<<1, NB, 0, stream>>>(ghist, bbase, gcur, W3, Wf, w3f, wff);
    partition_kernel<<<nt, 256, 0, stream>>>(srcv, dstv, gcur, bedge, E, shift, NPB - 1);
    build_kernel<<<NB, 256, 0, stream>>>(bbase, bedge, x, off, dinv, adj, y0h);

    // L1: agg(y0h, 4MB table) + transform 8->16 -> planes y1a/y1b
    aggt1_kernel<<<N / 256, 256, 0, stream>>>(y0h, off, adj, dinv, W1, b1, y1a, y1b);
    // L2: two dim-split passes, each gathering a 4MB L2-resident plane
    aggt2a_kernel<<<N / 256, 256, 0, stream>>>(y1a, off, adj, Ppart);
    aggt2b_kernel<<<N / 256, 256, 0, stream>>>(y1b, off, adj, dinv, Ppart, W2, b2, y2b);
    // L3: agg(y2b) -> a3h (fp16, in bufA; y0h dead), then MFMA transform+FC -> out
    agg3_kernel<<<(N * 4) / 256, 256, 0, stream>>>(y2b, off, adj, dinv, a3h, N);
    t3fc_kernel<<<N / 64, 256, 0, stream>>>(a3h, w3f, b3, wff, bf, (float*)d_out);
}

// Round 9
// 285.883 us; speedup vs baseline: 1.1188x; 1.0506x over previous
//
#include <hip/hip_runtime.h>
#include <hip/hip_bf16.h>

// GCN x3 + FC on a fixed random graph.
//   1. Bucket-partition CSR build: hist -> scan -> packed partition
//      (src|dl<<18) -> per-bucket build (LDS atomics, coalesced I/O) with
//      fused prescale y0 = dinv*x (fp16).
//   2. Pull aggregation over pre-scaled features y = dinv*h:
//      out[v] = dinv[v]*(sum y[s] + y[v]).  All inter-layer features fp16.
//   3. R16: revert R15 (dim-split + NT stores REGRESSED: NT stores left y2b
//      cold for agg3 -> FETCH 129MB ~= E*64B, +8us; and table fetch is
//      compulsory ~table*8XCD regardless of splitting).  Keep R13 structure;
//      gather loops become MASKED BURST-8: clamp idx to end-1, cndmask
//      masked rows to 0 -> ceil(deg/8) rounds of 8 parallel gathers (R13's
//      2/1-wide tails were 3-4 DEPENDENT miss rounds/node; that's why aggt2
//      ran 2.2TB/s vs agg3's measured 3.4TB/s random-sector ceiling).
//      NT loads on adj only (stream; protects table residency); stores
//      plain (keeps y2b warm for agg3).
//   4. t3fc (R10): MFMA mfma_f32_16x16x32_f16; weights pre-converted to
//      B-frag-ordered fp16 in bscan; per-wave 2KB LDS relu scratch.

#define NB   256     // dst buckets
#define NPB  1024    // nodes per bucket (N = NB*NPB)
#define TILE 4096    // edges per partition tile
#define SRCMASK 0x3FFFFu

typedef _Float16 half8 __attribute__((ext_vector_type(8)));
typedef float float4v __attribute__((ext_vector_type(4)));
typedef unsigned int u32x4 __attribute__((ext_vector_type(4)));

__device__ __forceinline__ unsigned pkh(float a, float b) {  // 2x fp32 -> packed fp16 (RNE)
    unsigned short ua = __builtin_bit_cast(unsigned short, (_Float16)a);
    unsigned short ub = __builtin_bit_cast(unsigned short, (_Float16)b);
    return (unsigned)ua | ((unsigned)ub << 16);
}
__device__ __forceinline__ float h_lo(unsigned u) {
    return (float)__builtin_bit_cast(_Float16, (unsigned short)(u & 0xFFFFu));
}
__device__ __forceinline__ float h_hi(unsigned u) {
    return (float)__builtin_bit_cast(_Float16, (unsigned short)(u >> 16));
}
__device__ __forceinline__ int ld_nt(const int* p) { return __builtin_nontemporal_load(p); }

#define UNPK8_ADD(A, u) \
    A##0 += h_lo(u.x); A##1 += h_hi(u.x); A##2 += h_lo(u.y); A##3 += h_hi(u.y); \
    A##4 += h_lo(u.z); A##5 += h_hi(u.z); A##6 += h_lo(u.w); A##7 += h_hi(u.w);

// ---- P1: global bucket histogram -------------------------------------------
__global__ void hist_kernel(const int* __restrict__ dst, int* __restrict__ ghist,
                            int E, int shift) {
    __shared__ int h[NB];
    int tid = threadIdx.x;
    h[tid] = 0;
    __syncthreads();
    int base = blockIdx.x * TILE;
    int cnt = min(TILE, E - base);
    for (int i = tid; i < cnt; i += 256)
        atomicAdd(&h[dst[base + i] >> shift], 1);
    __syncthreads();
    int v = h[tid];
    if (v) atomicAdd(&ghist[tid], v);
}

// ---- P2: scan bucket counts + weight->fp16 frag conversion -----------------
// Frag order for B of mfma_f32_16x16x32_f16: dest[( (k>>5)*4 + (j>>4) )*512
//  + (j&15)*32 + ((k>>3)&3)*8 + (k&7)]  (j = col, k = row of W[k][j]).
__global__ void bscan_kernel(const int* __restrict__ ghist, int* __restrict__ bbase,
                             int* __restrict__ gcursor,
                             const float* __restrict__ W3, const float* __restrict__ Wf,
                             _Float16* __restrict__ w3f, _Float16* __restrict__ wff) {
    __shared__ int sh[NB];
    int tid = threadIdx.x;
    int v = ghist[tid];
    sh[tid] = v;
    __syncthreads();
    for (int o = 1; o < NB; o <<= 1) {
        int t = (tid >= o) ? sh[tid - o] : 0;
        __syncthreads();
        sh[tid] += t;
        __syncthreads();
    }
    int incl = sh[tid];
    bbase[tid] = incl - v;
    gcursor[tid] = incl - v;
    if (tid == NB - 1) bbase[NB] = incl;
    // W3: [32][64]
    for (int i = tid; i < 32 * 64; i += NB) {
        int k = i >> 6, j = i & 63;
        w3f[(j >> 4) * 512 + (j & 15) * 32 + (k >> 3) * 8 + (k & 7)] = (_Float16)W3[i];
    }
    // Wf: [64][64]
    for (int i = tid; i < 64 * 64; i += NB) {
        int k = i >> 6, j = i & 63;
        wff[((k >> 5) * 4 + (j >> 4)) * 512 + (j & 15) * 32 + ((k >> 3) & 3) * 8 + (k & 7)]
            = (_Float16)Wf[i];
    }
}

// ---- P3: partition edges into bucket-contiguous packed stream --------------
__global__ void __launch_bounds__(256)
partition_kernel(const int* __restrict__ src, const int* __restrict__ dst,
                 int* __restrict__ gcursor, unsigned int* __restrict__ bedge,
                 int E, int shift, int mask) {
    __shared__ int h[NB], st[NB], gp[NB];
    __shared__ unsigned short rk[TILE];
    __shared__ int sd[TILE];
    __shared__ int ss[TILE];
    int tid = threadIdx.x;
    h[tid] = 0;
    __syncthreads();
    int base = blockIdx.x * TILE;
    int cnt = min(TILE, E - base);
    for (int i = tid; i < cnt; i += 256)
        rk[i] = (unsigned short)atomicAdd(&h[dst[base + i] >> shift], 1);
    __syncthreads();
    int hv = h[tid];
    st[tid] = hv;
    __syncthreads();
    for (int o = 1; o < NB; o <<= 1) {
        int t = (tid >= o) ? st[tid - o] : 0;
        __syncthreads();
        st[tid] += t;
        __syncthreads();
    }
    st[tid] -= hv;
    gp[tid] = hv ? atomicAdd(&gcursor[tid], hv) : 0;
    __syncthreads();
    for (int i = tid; i < cnt; i += 256) {
        int d = dst[base + i];
        int b = d >> shift;
        int pos = st[b] + rk[i];
        sd[pos] = d;
        ss[pos] = src[base + i];
    }
    __syncthreads();
    for (int i = tid; i < cnt; i += 256) {
        int d = sd[i];
        int b = d >> shift;
        int g = gp[b] + (i - st[b]);
        bedge[g] = (unsigned int)ss[i] | ((unsigned int)(d & mask) << 18);
    }
}

// ---- P4: per-bucket CSR build + fused prescale (fp16 y0) -------------------
__global__ void __launch_bounds__(256)
build_kernel(const int* __restrict__ bbase, const unsigned int* __restrict__ bedge,
             const float* __restrict__ x,
             int* __restrict__ off, float* __restrict__ dinv, int* __restrict__ adj,
             _Float16* __restrict__ y0h) {
    __shared__ int deg1[NPB];
    __shared__ int cur[NPB];
    __shared__ int bs[256];
    int tid = threadIdx.x;
    int b = blockIdx.x;
    int s = bbase[b], e = bbase[b + 1];
    int base = tid * 4;
#pragma unroll
    for (int i = 0; i < 4; i++) deg1[base + i] = 0;
    __syncthreads();
    for (int i = s + tid; i < e; i += 256)
        atomicAdd(&deg1[bedge[i] >> 18], 1);
    __syncthreads();
    int d0 = deg1[base], d1 = deg1[base + 1], d2 = deg1[base + 2], d3 = deg1[base + 3];
    int th = d0 + d1 + d2 + d3;
    bs[tid] = th;
    __syncthreads();
    for (int o = 1; o < 256; o <<= 1) {
        int t = (tid >= o) ? bs[tid - o] : 0;
        __syncthreads();
        bs[tid] += t;
        __syncthreads();
    }
    int run = s + bs[tid] - th;
    int vb = b * NPB + base;
    off[vb]     = run; cur[base]     = run; dinv[vb]     = rsqrtf((float)(d0 + 1)); run += d0;
    off[vb + 1] = run; cur[base + 1] = run; dinv[vb + 1] = rsqrtf((float)(d1 + 1)); run += d1;
    off[vb + 2] = run; cur[base + 2] = run; dinv[vb + 2] = rsqrtf((float)(d2 + 1)); run += d2;
    off[vb + 3] = run; cur[base + 3] = run; dinv[vb + 3] = rsqrtf((float)(d3 + 1)); run += d3;
    if (b == NB - 1 && tid == 255) off[NB * NPB] = e;   // sentinel off[N] = E
    __syncthreads();
    for (int i = s + tid; i < e; i += 256) {
        unsigned int pk = bedge[i];
        int p = atomicAdd(&cur[pk >> 18], 1);
        adj[p] = (int)(pk & SRCMASK);
    }
    // fused prescale: y0h[v] = fp16(dinv[v] * x[v])  (bucket rows, coalesced)
    for (int i = tid; i < NPB; i += 256) {
        float dv = rsqrtf((float)(deg1[i] + 1));
        const float4* xr = (const float4*)x + (size_t)(b * NPB + i) * 2;
        float4 t0 = xr[0], t1 = xr[1];
        uint4 pk;
        pk.x = pkh(t0.x * dv, t0.y * dv); pk.y = pkh(t0.z * dv, t0.w * dv);
        pk.z = pkh(t1.x * dv, t1.y * dv); pk.w = pkh(t1.z * dv, t1.w * dv);
        ((uint4*)y0h)[(size_t)b * NPB + i] = pk;
    }
}

// ---- Fused agg(8-dim fp16) + transform 8->16 -> fp16 y1 --------------------
// 1 lane/node, full 16B row per gather; MASKED BURST-8: all 8 gathers of a
// round issued before any use; padded lanes clamped to end-1 and zeroed.
__global__ void __launch_bounds__(256)
aggt1_kernel(const _Float16* __restrict__ y0h, const int* __restrict__ off,
             const int* __restrict__ adj, const float* __restrict__ dinv,
             const float* __restrict__ W1, const float* __restrict__ b1,
             _Float16* __restrict__ y1h) {
    __shared__ float Ws[8 * 16];
    __shared__ float bsh[16];
    const int tid = threadIdx.x;
    if (tid < 128) Ws[tid] = W1[tid];
    if (tid < 16) bsh[tid] = b1[tid];
    const int vg = blockIdx.x * 256 + tid;
    const u32x4* y4 = (const u32x4*)y0h;
    int beg = off[vg], end = off[vg + 1];
    u32x4 us = y4[vg];   // self (full row)
    float a0 = h_lo(us.x), a1 = h_hi(us.x), a2 = h_lo(us.y), a3 = h_hi(us.y),
          a4 = h_lo(us.z), a5 = h_hi(us.z), a6 = h_lo(us.w), a7 = h_hi(us.w);
    float c0 = 0, c1 = 0, c2 = 0, c3 = 0, c4 = 0, c5 = 0, c6 = 0, c7 = 0;
    u32x4 zz; zz.x = 0; zz.y = 0; zz.z = 0; zz.w = 0;
    for (int eb = beg; eb < end; eb += 8) {
        int i0 = ld_nt(adj + eb);
        int i1 = ld_nt(adj + min(eb + 1, end - 1));
        int i2 = ld_nt(adj + min(eb + 2, end - 1));
        int i3 = ld_nt(adj + min(eb + 3, end - 1));
        int i4 = ld_nt(adj + min(eb + 4, end - 1));
        int i5 = ld_nt(adj + min(eb + 5, end - 1));
        int i6 = ld_nt(adj + min(eb + 6, end - 1));
        int i7 = ld_nt(adj + min(eb + 7, end - 1));
        u32x4 u0 = y4[i0], u1 = y4[i1], u2 = y4[i2], u3 = y4[i3];
        u32x4 u4 = y4[i4], u5 = y4[i5], u6 = y4[i6], u7 = y4[i7];
        u1 = (eb + 1 < end) ? u1 : zz;
        u2 = (eb + 2 < end) ? u2 : zz;
        u3 = (eb + 3 < end) ? u3 : zz;
        u4 = (eb + 4 < end) ? u4 : zz;
        u5 = (eb + 5 < end) ? u5 : zz;
        u6 = (eb + 6 < end) ? u6 : zz;
        u7 = (eb + 7 < end) ? u7 : zz;
        UNPK8_ADD(a, u0) UNPK8_ADD(c, u1) UNPK8_ADD(a, u2) UNPK8_ADD(c, u3)
        UNPK8_ADD(a, u4) UNPK8_ADD(c, u5) UNPK8_ADD(a, u6) UNPK8_ADD(c, u7)
    }
    float dv = dinv[vg];
    float in[8];
    in[0] = (a0 + c0) * dv; in[1] = (a1 + c1) * dv;
    in[2] = (a2 + c2) * dv; in[3] = (a3 + c3) * dv;
    in[4] = (a4 + c4) * dv; in[5] = (a5 + c5) * dv;
    in[6] = (a6 + c6) * dv; in[7] = (a7 + c7) * dv;
    __syncthreads();   // Ws/bsh visibility
    const float4* W4 = (const float4*)Ws;
    float o[16];
    {
        float4 b0 = ((const float4*)bsh)[0], b1v = ((const float4*)bsh)[1];
        float4 b2v = ((const float4*)bsh)[2], b3v = ((const float4*)bsh)[3];
        o[0] = b0.x; o[1] = b0.y; o[2] = b0.z; o[3] = b0.w;
        o[4] = b1v.x; o[5] = b1v.y; o[6] = b1v.z; o[7] = b1v.w;
        o[8] = b2v.x; o[9] = b2v.y; o[10] = b2v.z; o[11] = b2v.w;
        o[12] = b3v.x; o[13] = b3v.y; o[14] = b3v.z; o[15] = b3v.w;
    }
#pragma unroll
    for (int k = 0; k < 8; k++) {
        float xk = in[k];
        float4 w0 = W4[k * 4 + 0], w1 = W4[k * 4 + 1];
        float4 w2 = W4[k * 4 + 2], w3 = W4[k * 4 + 3];
        o[0] = fmaf(xk, w0.x, o[0]);  o[1] = fmaf(xk, w0.y, o[1]);
        o[2] = fmaf(xk, w0.z, o[2]);  o[3] = fmaf(xk, w0.w, o[3]);
        o[4] = fmaf(xk, w1.x, o[4]);  o[5] = fmaf(xk, w1.y, o[5]);
        o[6] = fmaf(xk, w1.z, o[6]);  o[7] = fmaf(xk, w1.w, o[7]);
        o[8] = fmaf(xk, w2.x, o[8]);  o[9] = fmaf(xk, w2.y, o[9]);
        o[10] = fmaf(xk, w2.z, o[10]); o[11] = fmaf(xk, w2.w, o[11]);
        o[12] = fmaf(xk, w3.x, o[12]); o[13] = fmaf(xk, w3.y, o[13]);
        o[14] = fmaf(xk, w3.z, o[14]); o[15] = fmaf(xk, w3.w, o[15]);
    }
    uint4 p0, p1;
    p0.x = pkh(dv * fmaxf(o[0], 0.f),  dv * fmaxf(o[1], 0.f));
    p0.y = pkh(dv * fmaxf(o[2], 0.f),  dv * fmaxf(o[3], 0.f));
    p0.z = pkh(dv * fmaxf(o[4], 0.f),  dv * fmaxf(o[5], 0.f));
    p0.w = pkh(dv * fmaxf(o[6], 0.f),  dv * fmaxf(o[7], 0.f));
    p1.x = pkh(dv * fmaxf(o[8], 0.f),  dv * fmaxf(o[9], 0.f));
    p1.y = pkh(dv * fmaxf(o[10], 0.f), dv * fmaxf(o[11], 0.f));
    p1.z = pkh(dv * fmaxf(o[12], 0.f), dv * fmaxf(o[13], 0.f));
    p1.w = pkh(dv * fmaxf(o[14], 0.f), dv * fmaxf(o[15], 0.f));
    uint4* out4 = (uint4*)y1h;
    out4[(size_t)vg * 2]     = p0;
    out4[(size_t)vg * 2 + 1] = p1;
}

// ---- Fused agg(16-dim fp16) + transform 16->32 -> fp16 y2 ------------------
// 2 lanes/node, 16B/gather, MASKED BURST-8 (16 in flight per node); halves
// exchanged via shfl_xor (no LDS staging); Ws as float4.
__global__ void __launch_bounds__(256)
aggt2_kernel(const _Float16* __restrict__ y1h, const int* __restrict__ off,
             const int* __restrict__ adj, const float* __restrict__ dinv,
             const float* __restrict__ W2, const float* __restrict__ b2,
             unsigned int* __restrict__ y2b) {
    __shared__ float Ws[16 * 32];
    __shared__ float bsh[32];
    const int tid = threadIdx.x;
    for (int i = tid; i < 16 * 32; i += 256) Ws[i] = W2[i];
    if (tid < 32) bsh[tid] = b2[tid];
    const int vbase = blockIdx.x * 128;
    const int vl = tid >> 1, c = tid & 1;
    const int vg = vbase + vl;
    const u32x4* y4 = (const u32x4*)y1h;
    int beg = off[vg], end = off[vg + 1];
    u32x4 us = y4[(size_t)vg * 2 + c];   // self half-row
    float a0 = h_lo(us.x), a1 = h_hi(us.x), a2 = h_lo(us.y), a3 = h_hi(us.y),
          a4 = h_lo(us.z), a5 = h_hi(us.z), a6 = h_lo(us.w), a7 = h_hi(us.w);
    float c0 = 0, c1 = 0, c2 = 0, c3 = 0, c4 = 0, c5 = 0, c6 = 0, c7 = 0;
    u32x4 zz; zz.x = 0; zz.y = 0; zz.z = 0; zz.w = 0;
    for (int eb = beg; eb < end; eb += 8) {
        int i0 = ld_nt(adj + eb);
        int i1 = ld_nt(adj + min(eb + 1, end - 1));
        int i2 = ld_nt(adj + min(eb + 2, end - 1));
        int i3 = ld_nt(adj + min(eb + 3, end - 1));
        int i4 = ld_nt(adj + min(eb + 4, end - 1));
        int i5 = ld_nt(adj + min(eb + 5, end - 1));
        int i6 = ld_nt(adj + min(eb + 6, end - 1));
        int i7 = ld_nt(adj + min(eb + 7, end - 1));
        u32x4 u0 = y4[(size_t)i0 * 2 + c], u1 = y4[(size_t)i1 * 2 + c];
        u32x4 u2 = y4[(size_t)i2 * 2 + c], u3 = y4[(size_t)i3 * 2 + c];
        u32x4 u4 = y4[(size_t)i4 * 2 + c], u5 = y4[(size_t)i5 * 2 + c];
        u32x4 u6 = y4[(size_t)i6 * 2 + c], u7 = y4[(size_t)i7 * 2 + c];
        u1 = (eb + 1 < end) ? u1 : zz;
        u2 = (eb + 2 < end) ? u2 : zz;
        u3 = (eb + 3 < end) ? u3 : zz;
        u4 = (eb + 4 < end) ? u4 : zz;
        u5 = (eb + 5 < end) ? u5 : zz;
        u6 = (eb + 6 < end) ? u6 : zz;
        u7 = (eb + 7 < end) ? u7 : zz;
        UNPK8_ADD(a, u0) UNPK8_ADD(c, u1) UNPK8_ADD(a, u2) UNPK8_ADD(c, u3)
        UNPK8_ADD(a, u4) UNPK8_ADD(c, u5) UNPK8_ADD(a, u6) UNPK8_ADD(c, u7)
    }
    float dv = dinv[vg];
    float own[8];
    own[0] = (a0 + c0) * dv; own[1] = (a1 + c1) * dv;
    own[2] = (a2 + c2) * dv; own[3] = (a3 + c3) * dv;
    own[4] = (a4 + c4) * dv; own[5] = (a5 + c5) * dv;
    own[6] = (a6 + c6) * dv; own[7] = (a7 + c7) * dv;
    // exchange halves: lane c holds dims [c*8, c*8+8); partner has the rest
    float oth[8];
#pragma unroll
    for (int k = 0; k < 8; k++) oth[k] = __shfl_xor(own[k], 1);
    float in[16];
#pragma unroll
    for (int k = 0; k < 8; k++) {
        in[c * 8 + k] = own[k];
        in[(1 - c) * 8 + k] = oth[k];
    }
    __syncthreads();   // Ws/bsh visibility
    // transform: lane c -> outputs j0 = c*16 .. +15; Ws row pitch 32 floats
    const int j0 = c * 16;
    const float4* W4 = (const float4*)Ws;   // 8 float4 per k-row
    float o[16];
#pragma unroll
    for (int jj = 0; jj < 16; jj += 4) {
        float4 bv = *(const float4*)&bsh[j0 + jj];
        o[jj] = bv.x; o[jj + 1] = bv.y; o[jj + 2] = bv.z; o[jj + 3] = bv.w;
    }
#pragma unroll
    for (int k = 0; k < 16; k++) {
        float xk = in[k];
        float4 w0 = W4[k * 8 + c * 4 + 0], w1 = W4[k * 8 + c * 4 + 1];
        float4 w2 = W4[k * 8 + c * 4 + 2], w3 = W4[k * 8 + c * 4 + 3];
        o[0] = fmaf(xk, w0.x, o[0]);  o[1] = fmaf(xk, w0.y, o[1]);
        o[2] = fmaf(xk, w0.z, o[2]);  o[3] = fmaf(xk, w0.w, o[3]);
        o[4] = fmaf(xk, w1.x, o[4]);  o[5] = fmaf(xk, w1.y, o[5]);
        o[6] = fmaf(xk, w1.z, o[6]);  o[7] = fmaf(xk, w1.w, o[7]);
        o[8] = fmaf(xk, w2.x, o[8]);  o[9] = fmaf(xk, w2.y, o[9]);
        o[10] = fmaf(xk, w2.z, o[10]); o[11] = fmaf(xk, w2.w, o[11]);
        o[12] = fmaf(xk, w3.x, o[12]); o[13] = fmaf(xk, w3.y, o[13]);
        o[14] = fmaf(xk, w3.z, o[14]); o[15] = fmaf(xk, w3.w, o[15]);
    }
    uint4 p0, p1;
    p0.x = pkh(dv * fmaxf(o[0], 0.f),  dv * fmaxf(o[1], 0.f));
    p0.y = pkh(dv * fmaxf(o[2], 0.f),  dv * fmaxf(o[3], 0.f));
    p0.z = pkh(dv * fmaxf(o[4], 0.f),  dv * fmaxf(o[5], 0.f));
    p0.w = pkh(dv * fmaxf(o[6], 0.f),  dv * fmaxf(o[7], 0.f));
    p1.x = pkh(dv * fmaxf(o[8], 0.f),  dv * fmaxf(o[9], 0.f));
    p1.y = pkh(dv * fmaxf(o[10], 0.f), dv * fmaxf(o[11], 0.f));
    p1.z = pkh(dv * fmaxf(o[12], 0.f), dv * fmaxf(o[13], 0.f));
    p1.w = pkh(dv * fmaxf(o[14], 0.f), dv * fmaxf(o[15], 0.f));
    uint4* out4 = (uint4*)y2b;
    out4[(size_t)vg * 4 + c * 2]     = p0;
    out4[(size_t)vg * 4 + c * 2 + 1] = p1;
}

// ---- agg(32-dim, fp16 rows) -> fp16 a3 -------------------------------------
// 4 lanes/node, each lane one 16B (8 fp16) chunk; MASKED BURST-8.
__global__ void __launch_bounds__(256)
agg3_kernel(const unsigned int* __restrict__ y2b, const int* __restrict__ off,
            const int* __restrict__ adj, const float* __restrict__ dinv,
            _Float16* __restrict__ a3out, int n) {
    int t = blockIdx.x * 256 + threadIdx.x;
    int v = t >> 2, c = t & 3;
    if (v >= n) return;
    const u32x4* yb = (const u32x4*)y2b;
    u32x4 us = yb[(size_t)v * 4 + c];   // self
    float a0 = h_lo(us.x), a1 = h_hi(us.x), a2 = h_lo(us.y), a3 = h_hi(us.y),
          a4 = h_lo(us.z), a5 = h_hi(us.z), a6 = h_lo(us.w), a7 = h_hi(us.w);
    float c0 = 0, c1 = 0, c2 = 0, c3 = 0, c4 = 0, c5 = 0, c6 = 0, c7 = 0;
    int beg = off[v], end = off[v + 1];
    u32x4 zz; zz.x = 0; zz.y = 0; zz.z = 0; zz.w = 0;
    for (int eb = beg; eb < end; eb += 8) {
        int i0 = ld_nt(adj + eb);
        int i1 = ld_nt(adj + min(eb + 1, end - 1));
        int i2 = ld_nt(adj + min(eb + 2, end - 1));
        int i3 = ld_nt(adj + min(eb + 3, end - 1));
        int i4 = ld_nt(adj + min(eb + 4, end - 1));
        int i5 = ld_nt(adj + min(eb + 5, end - 1));
        int i6 = ld_nt(adj + min(eb + 6, end - 1));
        int i7 = ld_nt(adj + min(eb + 7, end - 1));
        u32x4 u0 = yb[(size_t)i0 * 4 + c], u1 = yb[(size_t)i1 * 4 + c];
        u32x4 u2 = yb[(size_t)i2 * 4 + c], u3 = yb[(size_t)i3 * 4 + c];
        u32x4 u4 = yb[(size_t)i4 * 4 + c], u5 = yb[(size_t)i5 * 4 + c];
        u32x4 u6 = yb[(size_t)i6 * 4 + c], u7 = yb[(size_t)i7 * 4 + c];
        u1 = (eb + 1 < end) ? u1 : zz;
        u2 = (eb + 2 < end) ? u2 : zz;
        u3 = (eb + 3 < end) ? u3 : zz;
        u4 = (eb + 4 < end) ? u4 : zz;
        u5 = (eb + 5 < end) ? u5 : zz;
        u6 = (eb + 6 < end) ? u6 : zz;
        u7 = (eb + 7 < end) ? u7 : zz;
        UNPK8_ADD(a, u0) UNPK8_ADD(c, u1) UNPK8_ADD(a, u2) UNPK8_ADD(c, u3)
        UNPK8_ADD(a, u4) UNPK8_ADD(c, u5) UNPK8_ADD(a, u6) UNPK8_ADD(c, u7)
    }
    float dv = dinv[v];
    u32x4 st;
    st.x = pkh((a0 + c0) * dv, (a1 + c1) * dv);
    st.y = pkh((a2 + c2) * dv, (a3 + c3) * dv);
    st.z = pkh((a4 + c4) * dv, (a5 + c5) * dv);
    st.w = pkh((a6 + c6) * dv, (a7 + c7) * dv);
    ((u32x4*)a3out)[(size_t)v * 4 + c] = st;
}

// ---- Fused layer-3 transform + FC via MFMA ---------------------------------
// 256 threads = 4 waves, 64 nodes/block (16 per wave).  No __syncthreads:
// B-frags come straight from global (frag-ordered fp16, L1-hot), the only
// LDS is a per-wave 2KB frag-ordered relu(t) scratch (contiguous 16B/lane
// reads -> conflict-free).  Intra-wave LDS dep: compiler-inserted lgkmcnt.
__global__ void __launch_bounds__(256)
t3fc_kernel(const _Float16* __restrict__ a3h,
            const _Float16* __restrict__ w3f, const float* __restrict__ b3,
            const _Float16* __restrict__ wff, const float* __restrict__ bf,
            float* __restrict__ out) {
    __shared__ __align__(16) _Float16 tA[4][1024];   // [wave][ks*512 + row*32 + h*8 + e]
    const int tid = threadIdx.x;
    const int w = tid >> 6, l = tid & 63;
    const int lr = l & 15, lh = l >> 4;
    const int vbase = blockIdx.x * 64 + w * 16;
    const int fragoff = lr * 32 + lh * 8;

    // A1: node row = vbase+lr, k = lh*8..lh*8+7 (fp16, 16B/lane)
    half8 A1 = *(const half8*)(a3h + (size_t)(vbase + lr) * 32 + lh * 8);

    // GEMM1: 4 col-tiles, K=32 in one MFMA each
    float4v c1[4];
#pragma unroll
    for (int nt = 0; nt < 4; nt++) {
        float bv = b3[nt * 16 + lr];                  // D col = nt*16+lr
        float4v ci = {bv, bv, bv, bv};
        half8 B = *(const half8*)(w3f + nt * 512 + fragoff);
        c1[nt] = __builtin_amdgcn_mfma_f32_16x16x32_f16(A1, B, ci, 0, 0, 0);
    }

    // relu -> fp16 -> per-wave frag-ordered scratch.
    // D elem (row = lh*4+r, col = nt*16+lr) becomes t[row][k2=col]:
    //   idx = (k2>>5)*512 + row*32 + ((k2>>3)&3)*8 + (k2&7)
    _Float16* tw = tA[w];
#pragma unroll
    for (int nt = 0; nt < 4; nt++) {
        int k2 = nt * 16 + lr;
        int base = (k2 >> 5) * 512 + ((k2 >> 3) & 3) * 8 + (k2 & 7);
#pragma unroll
        for (int r = 0; r < 4; r++)
            tw[base + (lh * 4 + r) * 32] = (_Float16)fmaxf(c1[nt][r], 0.f);
    }

    // GEMM2: K=64 = 2 k-steps x 4 col-tiles
    float4v c2[4];
#pragma unroll
    for (int nt = 0; nt < 4; nt++) {
        float bv = bf[nt * 16 + lr];
        c2[nt] = (float4v){bv, bv, bv, bv};
    }
#pragma unroll
    for (int ks = 0; ks < 2; ks++) {
        half8 A2 = *(const half8*)(tw + ks * 512 + fragoff);
#pragma unroll
        for (int nt = 0; nt < 4; nt++) {
            half8 B = *(const half8*)(wff + (ks * 4 + nt) * 512 + fragoff);
            c2[nt] = __builtin_amdgcn_mfma_f32_16x16x32_f16(A2, B, c2[nt], 0, 0, 0);
        }
    }

    // store: D elem (row = lh*4+r, col = nt*16+lr); 64B segments per (nt,r)
#pragma unroll
    for (int nt = 0; nt < 4; nt++) {
#pragma unroll
        for (int r = 0; r < 4; r++)
            out[(size_t)(vbase + lh * 4 + r) * 64 + nt * 16 + lr] = c2[nt][r];
    }
}

extern "C" void kernel_launch(void* const* d_in, const int* in_sizes, int n_in,
                              void* d_out, int out_size, void* d_ws, size_t ws_size,
                              hipStream_t stream) {
    const float* x  = (const float*)d_in[0];
    const float* W1 = (const float*)d_in[1];
    const float* b1 = (const float*)d_in[2];
    const float* W2 = (const float*)d_in[3];
    const float* b2 = (const float*)d_in[4];
    const float* W3 = (const float*)d_in[5];
    const float* b3 = (const float*)d_in[6];
    const float* Wf = (const float*)d_in[7];
    const float* bf = (const float*)d_in[8];
    const int*   ei = (const int*)d_in[9];

    const int N = in_sizes[0] / 8;   // 262144
    const int E = in_sizes[9] / 2;   // 2097152
    const int* srcv = ei;
    const int* dstv = ei + E;
    const int shift = 10;            // log2(NPB)

    // Workspace layout (64B-aligned chunks)
    char* p = (char*)d_ws;
    auto take = [&p](size_t bytes) { char* q = p; p += (bytes + 63) & ~size_t(63); return q; };
    int*   off   = (int*)take((size_t)(N + 16) * 4);
    float* dinv  = (float*)take((size_t)N * 4);
    int*   adj   = (int*)take((size_t)E * 4);
    int*   ghist = (int*)take(NB * 4);
    int*   bbase = (int*)take((NB + 1) * 4);
    int*   gcur  = (int*)take(NB * 4);
    _Float16* w3f = (_Float16*)take(32 * 64 * 2);      // frag-ordered fp16 W3
    _Float16* wff = (_Float16*)take(64 * 64 * 2);      // frag-ordered fp16 Wf
    char*  bufA  = take((size_t)N * 32 * 4);           // y0h (4MB) then a3h (fp16, 16MB)
    char*  bufB  = take((size_t)N * 16 * 4);           // y1h (fp16, 8MB)
    char*  regX  = take((size_t)N * 32 * 2);           // 16MB: bedge (8MB) then y2b (fp16)
    unsigned int* bedge = (unsigned int*)regX;
    unsigned int* y2b   = (unsigned int*)regX;
    _Float16* y0h = (_Float16*)bufA;
    _Float16* a3h = (_Float16*)bufA;
    _Float16* y1h = (_Float16*)bufB;

    hipMemsetAsync(ghist, 0, NB * 4, stream);

    int nt = (E + TILE - 1) / TILE;  // 512 tiles
    hist_kernel<<<nt, 256, 0, stream>>>(dstv, ghist, E, shift);
    bscan_kernel<<<1, NB, 0, stream>>>(ghist, bbase, gcur, W3, Wf, w3f, wff);
    partition_kernel<<<nt, 256, 0, stream>>>(srcv, dstv, gcur, bedge, E, shift, NPB - 1);
    build_kernel<<<NB, 256, 0, stream>>>(bbase, bedge, x, off, dinv, adj, y0h);

    // L1: agg(y0h) + transform 8->16 -> y1h (fp16)
    aggt1_kernel<<<N / 256, 256, 0, stream>>>(y0h, off, adj, dinv, W1, b1, y1h);
    // L2: agg(y1h) + transform 16->32 -> y2b (fp16; overwrites dead bedge)
    aggt2_kernel<<<N / 128, 256, 0, stream>>>(y1h, off, adj, dinv, W2, b2, y2b);
    // L3: agg(y2b) -> a3h (fp16, in bufA; y0h dead), then MFMA transform+FC -> out
    agg3_kernel<<<(N * 4) / 256, 256, 0, stream>>>(y2b, off, adj, dinv, a3h, N);
    t3fc_kernel<<<N / 64, 256, 0, stream>>>(a3h, w3f, b3, wff, bf, (float*)d_out);
}

// Round 10
// 280.929 us; speedup vs baseline: 1.1386x; 1.0176x over previous
//
#include <hip/hip_runtime.h>
#include <hip/hip_bf16.h>

// GCN x3 + FC on a fixed random graph.
//   1. Bucket-partition CSR build: hist -> scan -> packed partition
//      (src|dl<<18) -> per-bucket build (LDS atomics, coalesced I/O) with
//      fused prescale y0 = dinv*x (fp16).
//   2. Pull aggregation over pre-scaled features y = dinv*h:
//      out[v] = dinv[v]*(sum y[s] + y[v]).  All inter-layer features fp16.
//   3. Agg lessons (R13-R16): random-sector gather is the floor; FETCH is at
//      compulsory minimum (table*8XCD + adj + write); degree-sort (+36MB
//      scatter) and dim-split (+NT cold start) REGRESSED; burst masking was
//      null (queues already full).  R17: aggt2 gathers the full 32B row with
//      ONE lane/node (1 sector per request vs half -- agg3's 64B/4-lane
//      pattern runs 3.4TB/s vs aggt2's 2.5); transform = 32 outputs/lane.
//   4. R17: agg3 FUSED into t3fc.  Each wave aggregates its 16 nodes
//      (4 lanes/node, burst-8, identical numerics incl. fp16 RNE link) into
//      a per-wave LDS tile (pitch 40 halves: 16B-aligned rows, <=2-way
//      banks), then reads A-frags from LDS and runs GEMM1/GEMM2 (MFMA
//      mfma_f32_16x16x32_f16, weights B-frag-preordered in bscan).  Saves
//      the 32MB a3 round-trip; all intra-wave, no barrier.

#define NB   256     // dst buckets
#define NPB  1024    // nodes per bucket (N = NB*NPB)
#define TILE 4096    // edges per partition tile
#define SRCMASK 0x3FFFFu

typedef _Float16 half8 __attribute__((ext_vector_type(8)));
typedef float float4v __attribute__((ext_vector_type(4)));
typedef unsigned int u32x4 __attribute__((ext_vector_type(4)));

__device__ __forceinline__ unsigned pkh(float a, float b) {  // 2x fp32 -> packed fp16 (RNE)
    unsigned short ua = __builtin_bit_cast(unsigned short, (_Float16)a);
    unsigned short ub = __builtin_bit_cast(unsigned short, (_Float16)b);
    return (unsigned)ua | ((unsigned)ub << 16);
}
__device__ __forceinline__ float h_lo(unsigned u) {
    return (float)__builtin_bit_cast(_Float16, (unsigned short)(u & 0xFFFFu));
}
__device__ __forceinline__ float h_hi(unsigned u) {
    return (float)__builtin_bit_cast(_Float16, (unsigned short)(u >> 16));
}
__device__ __forceinline__ int ld_nt(const int* p) { return __builtin_nontemporal_load(p); }

#define UNPK8_ADD(A, u) \
    A##0 += h_lo(u.x); A##1 += h_hi(u.x); A##2 += h_lo(u.y); A##3 += h_hi(u.y); \
    A##4 += h_lo(u.z); A##5 += h_hi(u.z); A##6 += h_lo(u.w); A##7 += h_hi(u.w);

#define UNPK16_ARR(A, ul, uh) \
    A[0] += h_lo(ul.x); A[1] += h_hi(ul.x); A[2] += h_lo(ul.y); A[3] += h_hi(ul.y); \
    A[4] += h_lo(ul.z); A[5] += h_hi(ul.z); A[6] += h_lo(ul.w); A[7] += h_hi(ul.w); \
    A[8] += h_lo(uh.x); A[9] += h_hi(uh.x); A[10] += h_lo(uh.y); A[11] += h_hi(uh.y); \
    A[12] += h_lo(uh.z); A[13] += h_hi(uh.z); A[14] += h_lo(uh.w); A[15] += h_hi(uh.w);

// ---- P1: global bucket histogram -------------------------------------------
__global__ void hist_kernel(const int* __restrict__ dst, int* __restrict__ ghist,
                            int E, int shift) {
    __shared__ int h[NB];
    int tid = threadIdx.x;
    h[tid] = 0;
    __syncthreads();
    int base = blockIdx.x * TILE;
    int cnt = min(TILE, E - base);
    for (int i = tid; i < cnt; i += 256)
        atomicAdd(&h[dst[base + i] >> shift], 1);
    __syncthreads();
    int v = h[tid];
    if (v) atomicAdd(&ghist[tid], v);
}

// ---- P2: scan bucket counts + weight->fp16 frag conversion -----------------
// Frag order for B of mfma_f32_16x16x32_f16: dest[( (k>>5)*4 + (j>>4) )*512
//  + (j&15)*32 + ((k>>3)&3)*8 + (k&7)]  (j = col, k = row of W[k][j]).
__global__ void bscan_kernel(const int* __restrict__ ghist, int* __restrict__ bbase,
                             int* __restrict__ gcursor,
                             const float* __restrict__ W3, const float* __restrict__ Wf,
                             _Float16* __restrict__ w3f, _Float16* __restrict__ wff) {
    __shared__ int sh[NB];
    int tid = threadIdx.x;
    int v = ghist[tid];
    sh[tid] = v;
    __syncthreads();
    for (int o = 1; o < NB; o <<= 1) {
        int t = (tid >= o) ? sh[tid - o] : 0;
        __syncthreads();
        sh[tid] += t;
        __syncthreads();
    }
    int incl = sh[tid];
    bbase[tid] = incl - v;
    gcursor[tid] = incl - v;
    if (tid == NB - 1) bbase[NB] = incl;
    // W3: [32][64]
    for (int i = tid; i < 32 * 64; i += NB) {
        int k = i >> 6, j = i & 63;
        w3f[(j >> 4) * 512 + (j & 15) * 32 + (k >> 3) * 8 + (k & 7)] = (_Float16)W3[i];
    }
    // Wf: [64][64]
    for (int i = tid; i < 64 * 64; i += NB) {
        int k = i >> 6, j = i & 63;
        wff[((k >> 5) * 4 + (j >> 4)) * 512 + (j & 15) * 32 + ((k >> 3) & 3) * 8 + (k & 7)]
            = (_Float16)Wf[i];
    }
}

// ---- P3: partition edges into bucket-contiguous packed stream --------------
__global__ void __launch_bounds__(256)
partition_kernel(const int* __restrict__ src, const int* __restrict__ dst,
                 int* __restrict__ gcursor, unsigned int* __restrict__ bedge,
                 int E, int shift, int mask) {
    __shared__ int h[NB], st[NB], gp[NB];
    __shared__ unsigned short rk[TILE];
    __shared__ int sd[TILE];
    __shared__ int ss[TILE];
    int tid = threadIdx.x;
    h[tid] = 0;
    __syncthreads();
    int base = blockIdx.x * TILE;
    int cnt = min(TILE, E - base);
    for (int i = tid; i < cnt; i += 256)
        rk[i] = (unsigned short)atomicAdd(&h[dst[base + i] >> shift], 1);
    __syncthreads();
    int hv = h[tid];
    st[tid] = hv;
    __syncthreads();
    for (int o = 1; o < NB; o <<= 1) {
        int t = (tid >= o) ? st[tid - o] : 0;
        __syncthreads();
        st[tid] += t;
        __syncthreads();
    }
    st[tid] -= hv;
    gp[tid] = hv ? atomicAdd(&gcursor[tid], hv) : 0;
    __syncthreads();
    for (int i = tid; i < cnt; i += 256) {
        int d = dst[base + i];
        int b = d >> shift;
        int pos = st[b] + rk[i];
        sd[pos] = d;
        ss[pos] = src[base + i];
    }
    __syncthreads();
    for (int i = tid; i < cnt; i += 256) {
        int d = sd[i];
        int b = d >> shift;
        int g = gp[b] + (i - st[b]);
        bedge[g] = (unsigned int)ss[i] | ((unsigned int)(d & mask) << 18);
    }
}

// ---- P4: per-bucket CSR build + fused prescale (fp16 y0) -------------------
__global__ void __launch_bounds__(256)
build_kernel(const int* __restrict__ bbase, const unsigned int* __restrict__ bedge,
             const float* __restrict__ x,
             int* __restrict__ off, float* __restrict__ dinv, int* __restrict__ adj,
             _Float16* __restrict__ y0h) {
    __shared__ int deg1[NPB];
    __shared__ int cur[NPB];
    __shared__ int bs[256];
    int tid = threadIdx.x;
    int b = blockIdx.x;
    int s = bbase[b], e = bbase[b + 1];
    int base = tid * 4;
#pragma unroll
    for (int i = 0; i < 4; i++) deg1[base + i] = 0;
    __syncthreads();
    for (int i = s + tid; i < e; i += 256)
        atomicAdd(&deg1[bedge[i] >> 18], 1);
    __syncthreads();
    int d0 = deg1[base], d1 = deg1[base + 1], d2 = deg1[base + 2], d3 = deg1[base + 3];
    int th = d0 + d1 + d2 + d3;
    bs[tid] = th;
    __syncthreads();
    for (int o = 1; o < 256; o <<= 1) {
        int t = (tid >= o) ? bs[tid - o] : 0;
        __syncthreads();
        bs[tid] += t;
        __syncthreads();
    }
    int run = s + bs[tid] - th;
    int vb = b * NPB + base;
    off[vb]     = run; cur[base]     = run; dinv[vb]     = rsqrtf((float)(d0 + 1)); run += d0;
    off[vb + 1] = run; cur[base + 1] = run; dinv[vb + 1] = rsqrtf((float)(d1 + 1)); run += d1;
    off[vb + 2] = run; cur[base + 2] = run; dinv[vb + 2] = rsqrtf((float)(d2 + 1)); run += d2;
    off[vb + 3] = run; cur[base + 3] = run; dinv[vb + 3] = rsqrtf((float)(d3 + 1)); run += d3;
    if (b == NB - 1 && tid == 255) off[NB * NPB] = e;   // sentinel off[N] = E
    __syncthreads();
    for (int i = s + tid; i < e; i += 256) {
        unsigned int pk = bedge[i];
        int p = atomicAdd(&cur[pk >> 18], 1);
        adj[p] = (int)(pk & SRCMASK);
    }
    // fused prescale: y0h[v] = fp16(dinv[v] * x[v])  (bucket rows, coalesced)
    for (int i = tid; i < NPB; i += 256) {
        float dv = rsqrtf((float)(deg1[i] + 1));
        const float4* xr = (const float4*)x + (size_t)(b * NPB + i) * 2;
        float4 t0 = xr[0], t1 = xr[1];
        uint4 pk;
        pk.x = pkh(t0.x * dv, t0.y * dv); pk.y = pkh(t0.z * dv, t0.w * dv);
        pk.z = pkh(t1.x * dv, t1.y * dv); pk.w = pkh(t1.z * dv, t1.w * dv);
        ((uint4*)y0h)[(size_t)b * NPB + i] = pk;
    }
}

// ---- Fused agg(8-dim fp16) + transform 8->16 -> fp16 y1 --------------------
// 1 lane/node, full 16B row per gather; masked burst-8.
__global__ void __launch_bounds__(256)
aggt1_kernel(const _Float16* __restrict__ y0h, const int* __restrict__ off,
             const int* __restrict__ adj, const float* __restrict__ dinv,
             const float* __restrict__ W1, const float* __restrict__ b1,
             _Float16* __restrict__ y1h) {
    __shared__ float Ws[8 * 16];
    __shared__ float bsh[16];
    const int tid = threadIdx.x;
    if (tid < 128) Ws[tid] = W1[tid];
    if (tid < 16) bsh[tid] = b1[tid];
    const int vg = blockIdx.x * 256 + tid;
    const u32x4* y4 = (const u32x4*)y0h;
    int beg = off[vg], end = off[vg + 1];
    u32x4 us = y4[vg];   // self (full row)
    float a0 = h_lo(us.x), a1 = h_hi(us.x), a2 = h_lo(us.y), a3 = h_hi(us.y),
          a4 = h_lo(us.z), a5 = h_hi(us.z), a6 = h_lo(us.w), a7 = h_hi(us.w);
    float c0 = 0, c1 = 0, c2 = 0, c3 = 0, c4 = 0, c5 = 0, c6 = 0, c7 = 0;
    u32x4 zz; zz.x = 0; zz.y = 0; zz.z = 0; zz.w = 0;
    for (int eb = beg; eb < end; eb += 8) {
        int i0 = ld_nt(adj + eb);
        int i1 = ld_nt(adj + min(eb + 1, end - 1));
        int i2 = ld_nt(adj + min(eb + 2, end - 1));
        int i3 = ld_nt(adj + min(eb + 3, end - 1));
        int i4 = ld_nt(adj + min(eb + 4, end - 1));
        int i5 = ld_nt(adj + min(eb + 5, end - 1));
        int i6 = ld_nt(adj + min(eb + 6, end - 1));
        int i7 = ld_nt(adj + min(eb + 7, end - 1));
        u32x4 u0 = y4[i0], u1 = y4[i1], u2 = y4[i2], u3 = y4[i3];
        u32x4 u4 = y4[i4], u5 = y4[i5], u6 = y4[i6], u7 = y4[i7];
        u1 = (eb + 1 < end) ? u1 : zz;
        u2 = (eb + 2 < end) ? u2 : zz;
        u3 = (eb + 3 < end) ? u3 : zz;
        u4 = (eb + 4 < end) ? u4 : zz;
        u5 = (eb + 5 < end) ? u5 : zz;
        u6 = (eb + 6 < end) ? u6 : zz;
        u7 = (eb + 7 < end) ? u7 : zz;
        UNPK8_ADD(a, u0) UNPK8_ADD(c, u1) UNPK8_ADD(a, u2) UNPK8_ADD(c, u3)
        UNPK8_ADD(a, u4) UNPK8_ADD(c, u5) UNPK8_ADD(a, u6) UNPK8_ADD(c, u7)
    }
    float dv = dinv[vg];
    float in[8];
    in[0] = (a0 + c0) * dv; in[1] = (a1 + c1) * dv;
    in[2] = (a2 + c2) * dv; in[3] = (a3 + c3) * dv;
    in[4] = (a4 + c4) * dv; in[5] = (a5 + c5) * dv;
    in[6] = (a6 + c6) * dv; in[7] = (a7 + c7) * dv;
    __syncthreads();   // Ws/bsh visibility
    const float4* W4 = (const float4*)Ws;
    float o[16];
    {
        float4 b0 = ((const float4*)bsh)[0], b1v = ((const float4*)bsh)[1];
        float4 b2v = ((const float4*)bsh)[2], b3v = ((const float4*)bsh)[3];
        o[0] = b0.x; o[1] = b0.y; o[2] = b0.z; o[3] = b0.w;
        o[4] = b1v.x; o[5] = b1v.y; o[6] = b1v.z; o[7] = b1v.w;
        o[8] = b2v.x; o[9] = b2v.y; o[10] = b2v.z; o[11] = b2v.w;
        o[12] = b3v.x; o[13] = b3v.y; o[14] = b3v.z; o[15] = b3v.w;
    }
#pragma unroll
    for (int k = 0; k < 8; k++) {
        float xk = in[k];
        float4 w0 = W4[k * 4 + 0], w1 = W4[k * 4 + 1];
        float4 w2 = W4[k * 4 + 2], w3 = W4[k * 4 + 3];
        o[0] = fmaf(xk, w0.x, o[0]);  o[1] = fmaf(xk, w0.y, o[1]);
        o[2] = fmaf(xk, w0.z, o[2]);  o[3] = fmaf(xk, w0.w, o[3]);
        o[4] = fmaf(xk, w1.x, o[4]);  o[5] = fmaf(xk, w1.y, o[5]);
        o[6] = fmaf(xk, w1.z, o[6]);  o[7] = fmaf(xk, w1.w, o[7]);
        o[8] = fmaf(xk, w2.x, o[8]);  o[9] = fmaf(xk, w2.y, o[9]);
        o[10] = fmaf(xk, w2.z, o[10]); o[11] = fmaf(xk, w2.w, o[11]);
        o[12] = fmaf(xk, w3.x, o[12]); o[13] = fmaf(xk, w3.y, o[13]);
        o[14] = fmaf(xk, w3.z, o[14]); o[15] = fmaf(xk, w3.w, o[15]);
    }
    uint4 p0, p1;
    p0.x = pkh(dv * fmaxf(o[0], 0.f),  dv * fmaxf(o[1], 0.f));
    p0.y = pkh(dv * fmaxf(o[2], 0.f),  dv * fmaxf(o[3], 0.f));
    p0.z = pkh(dv * fmaxf(o[4], 0.f),  dv * fmaxf(o[5], 0.f));
    p0.w = pkh(dv * fmaxf(o[6], 0.f),  dv * fmaxf(o[7], 0.f));
    p1.x = pkh(dv * fmaxf(o[8], 0.f),  dv * fmaxf(o[9], 0.f));
    p1.y = pkh(dv * fmaxf(o[10], 0.f), dv * fmaxf(o[11], 0.f));
    p1.z = pkh(dv * fmaxf(o[12], 0.f), dv * fmaxf(o[13], 0.f));
    p1.w = pkh(dv * fmaxf(o[14], 0.f), dv * fmaxf(o[15], 0.f));
    uint4* out4 = (uint4*)y1h;
    out4[(size_t)vg * 2]     = p0;
    out4[(size_t)vg * 2 + 1] = p1;
}

// ---- Fused agg(16-dim fp16) + transform 16->32 -> fp16 y2 ------------------
// R17: 1 lane/node, full 32B row (2 loads, SAME 64B sector -> 1 sector per
// request, 64 sectors/wave-instr vs 32 with 2-lane); masked burst-4; no
// cross-lane exchange; transform = 32 outputs/lane.
__global__ void __launch_bounds__(256)
aggt2_kernel(const _Float16* __restrict__ y1h, const int* __restrict__ off,
             const int* __restrict__ adj, const float* __restrict__ dinv,
             const float* __restrict__ W2, const float* __restrict__ b2,
             unsigned int* __restrict__ y2b) {
    __shared__ float Ws[16 * 32];
    __shared__ float bsh[32];
    const int tid = threadIdx.x;
    for (int i = tid; i < 16 * 32; i += 256) Ws[i] = W2[i];
    if (tid < 32) bsh[tid] = b2[tid];
    const int vg = blockIdx.x * 256 + tid;
    const u32x4* y4 = (const u32x4*)y1h;
    int beg = off[vg], end = off[vg + 1];
    float A[16], C[16];
#pragma unroll
    for (int k = 0; k < 16; k++) { A[k] = 0.f; C[k] = 0.f; }
    {
        u32x4 usl = y4[(size_t)vg * 2], ush = y4[(size_t)vg * 2 + 1];   // self
        UNPK16_ARR(A, usl, ush)
    }
    u32x4 zz; zz.x = 0; zz.y = 0; zz.z = 0; zz.w = 0;
    for (int eb = beg; eb < end; eb += 4) {
        int i0 = ld_nt(adj + eb);
        int i1 = ld_nt(adj + min(eb + 1, end - 1));
        int i2 = ld_nt(adj + min(eb + 2, end - 1));
        int i3 = ld_nt(adj + min(eb + 3, end - 1));
        u32x4 u0l = y4[(size_t)i0 * 2], u0h = y4[(size_t)i0 * 2 + 1];
        u32x4 u1l = y4[(size_t)i1 * 2], u1h = y4[(size_t)i1 * 2 + 1];
        u32x4 u2l = y4[(size_t)i2 * 2], u2h = y4[(size_t)i2 * 2 + 1];
        u32x4 u3l = y4[(size_t)i3 * 2], u3h = y4[(size_t)i3 * 2 + 1];
        bool m1 = eb + 1 < end, m2 = eb + 2 < end, m3 = eb + 3 < end;
        u1l = m1 ? u1l : zz; u1h = m1 ? u1h : zz;
        u2l = m2 ? u2l : zz; u2h = m2 ? u2h : zz;
        u3l = m3 ? u3l : zz; u3h = m3 ? u3h : zz;
        UNPK16_ARR(A, u0l, u0h) UNPK16_ARR(C, u1l, u1h)
        UNPK16_ARR(A, u2l, u2h) UNPK16_ARR(C, u3l, u3h)
    }
    float dv = dinv[vg];
    float in[16];
#pragma unroll
    for (int k = 0; k < 16; k++) in[k] = (A[k] + C[k]) * dv;
    __syncthreads();   // Ws/bsh visibility
    const float4* W4 = (const float4*)Ws;   // 8 float4 per k-row
    float o[32];
#pragma unroll
    for (int jj = 0; jj < 32; jj += 4) {
        float4 bv = *(const float4*)&bsh[jj];
        o[jj] = bv.x; o[jj + 1] = bv.y; o[jj + 2] = bv.z; o[jj + 3] = bv.w;
    }
#pragma unroll
    for (int k = 0; k < 16; k++) {
        float xk = in[k];
#pragma unroll
        for (int q = 0; q < 8; q++) {
            float4 w = W4[k * 8 + q];
            o[q * 4 + 0] = fmaf(xk, w.x, o[q * 4 + 0]);
            o[q * 4 + 1] = fmaf(xk, w.y, o[q * 4 + 1]);
            o[q * 4 + 2] = fmaf(xk, w.z, o[q * 4 + 2]);
            o[q * 4 + 3] = fmaf(xk, w.w, o[q * 4 + 3]);
        }
    }
    u32x4* out4 = (u32x4*)y2b + (size_t)vg * 4;
#pragma unroll
    for (int q = 0; q < 4; q++) {
        u32x4 pk;
        pk.x = pkh(dv * fmaxf(o[q * 8 + 0], 0.f), dv * fmaxf(o[q * 8 + 1], 0.f));
        pk.y = pkh(dv * fmaxf(o[q * 8 + 2], 0.f), dv * fmaxf(o[q * 8 + 3], 0.f));
        pk.z = pkh(dv * fmaxf(o[q * 8 + 4], 0.f), dv * fmaxf(o[q * 8 + 5], 0.f));
        pk.w = pkh(dv * fmaxf(o[q * 8 + 6], 0.f), dv * fmaxf(o[q * 8 + 7], 0.f));
        out4[q] = pk;
    }
}

// ---- Fused agg(32-dim) + layer-3 transform + FC via MFMA -------------------
// 256 threads = 4 waves, 64 nodes/block (16 per wave).  Phase 1: each wave
// aggregates its 16 nodes (4 lanes/node, 16B chunk each, masked burst-8 --
// identical numerics to the old agg3 incl. the fp16 RNE link) into a
// per-wave LDS tile (pitch 40 halves = 80B rows: 16B-aligned, <=2-way
// banks).  Phase 2: A1-frags read from the tile, GEMM1 -> relu -> frag
// scratch -> GEMM2 -> store.  Everything intra-wave: NO barrier; compiler
// inserts lgkmcnt for the LDS write->read dependencies.
#define TIN_P 40
__global__ void __launch_bounds__(256)
agg3t3fc_kernel(const unsigned int* __restrict__ y2b, const int* __restrict__ off,
                const int* __restrict__ adj, const float* __restrict__ dinv,
                const _Float16* __restrict__ w3f, const float* __restrict__ b3,
                const _Float16* __restrict__ wff, const float* __restrict__ bf,
                float* __restrict__ out) {
    __shared__ __align__(16) _Float16 tin[4][16 * TIN_P];  // agg result tile
    __shared__ __align__(16) _Float16 tA[4][1024];         // relu(t) frag scratch
    const int tid = threadIdx.x;
    const int w = tid >> 6, l = tid & 63;
    const int vbase = blockIdx.x * 64 + w * 16;

    // ---- phase 1: aggregate this wave's 16 nodes ----
    {
        const int nl = l >> 2, c = l & 3;
        const int v = vbase + nl;
        const u32x4* yb = (const u32x4*)y2b;
        u32x4 us = yb[(size_t)v * 4 + c];   // self
        float a0 = h_lo(us.x), a1 = h_hi(us.x), a2 = h_lo(us.y), a3 = h_hi(us.y),
              a4 = h_lo(us.z), a5 = h_hi(us.z), a6 = h_lo(us.w), a7 = h_hi(us.w);
        float c0 = 0, c1 = 0, c2 = 0, c3 = 0, c4 = 0, c5 = 0, c6 = 0, c7 = 0;
        int beg = off[v], end = off[v + 1];
        u32x4 zz; zz.x = 0; zz.y = 0; zz.z = 0; zz.w = 0;
        for (int eb = beg; eb < end; eb += 8) {
            int i0 = ld_nt(adj + eb);
            int i1 = ld_nt(adj + min(eb + 1, end - 1));
            int i2 = ld_nt(adj + min(eb + 2, end - 1));
            int i3 = ld_nt(adj + min(eb + 3, end - 1));
            int i4 = ld_nt(adj + min(eb + 4, end - 1));
            int i5 = ld_nt(adj + min(eb + 5, end - 1));
            int i6 = ld_nt(adj + min(eb + 6, end - 1));
            int i7 = ld_nt(adj + min(eb + 7, end - 1));
            u32x4 u0 = yb[(size_t)i0 * 4 + c], u1 = yb[(size_t)i1 * 4 + c];
            u32x4 u2 = yb[(size_t)i2 * 4 + c], u3 = yb[(size_t)i3 * 4 + c];
            u32x4 u4 = yb[(size_t)i4 * 4 + c], u5 = yb[(size_t)i5 * 4 + c];
            u32x4 u6 = yb[(size_t)i6 * 4 + c], u7 = yb[(size_t)i7 * 4 + c];
            u1 = (eb + 1 < end) ? u1 : zz;
            u2 = (eb + 2 < end) ? u2 : zz;
            u3 = (eb + 3 < end) ? u3 : zz;
            u4 = (eb + 4 < end) ? u4 : zz;
            u5 = (eb + 5 < end) ? u5 : zz;
            u6 = (eb + 6 < end) ? u6 : zz;
            u7 = (eb + 7 < end) ? u7 : zz;
            UNPK8_ADD(a, u0) UNPK8_ADD(c, u1) UNPK8_ADD(a, u2) UNPK8_ADD(c, u3)
            UNPK8_ADD(a, u4) UNPK8_ADD(c, u5) UNPK8_ADD(a, u6) UNPK8_ADD(c, u7)
        }
        float dv = dinv[v];
        u32x4 pk;
        pk.x = pkh((a0 + c0) * dv, (a1 + c1) * dv);
        pk.y = pkh((a2 + c2) * dv, (a3 + c3) * dv);
        pk.z = pkh((a4 + c4) * dv, (a5 + c5) * dv);
        pk.w = pkh((a6 + c6) * dv, (a7 + c7) * dv);
        *(u32x4*)(tin[w] + nl * TIN_P + c * 8) = pk;   // byte off = nl*80+c*16, 16B-aligned
    }

    // ---- phase 2: GEMM1 (A1 from tin) ----
    const int lr = l & 15, lh = l >> 4;
    const int fragoff = lr * 32 + lh * 8;
    half8 A1 = *(const half8*)(tin[w] + lr * TIN_P + lh * 8);

    float4v c1[4];
#pragma unroll
    for (int nt = 0; nt < 4; nt++) {
        float bv = b3[nt * 16 + lr];                  // D col = nt*16+lr
        float4v ci = {bv, bv, bv, bv};
        half8 B = *(const half8*)(w3f + nt * 512 + fragoff);
        c1[nt] = __builtin_amdgcn_mfma_f32_16x16x32_f16(A1, B, ci, 0, 0, 0);
    }

    // relu -> fp16 -> per-wave frag-ordered scratch.
    // D elem (row = lh*4+r, col = nt*16+lr) becomes t[row][k2=col]:
    //   idx = (k2>>5)*512 + row*32 + ((k2>>3)&3)*8 + (k2&7)
    _Float16* tw = tA[w];
#pragma unroll
    for (int nt = 0; nt < 4; nt++) {
        int k2 = nt * 16 + lr;
        int base = (k2 >> 5) * 512 + ((k2 >> 3) & 3) * 8 + (k2 & 7);
#pragma unroll
        for (int r = 0; r < 4; r++)
            tw[base + (lh * 4 + r) * 32] = (_Float16)fmaxf(c1[nt][r], 0.f);
    }

    // GEMM2: K=64 = 2 k-steps x 4 col-tiles
    float4v c2[4];
#pragma unroll
    for (int nt = 0; nt < 4; nt++) {
        float bv = bf[nt * 16 + lr];
        c2[nt] = (float4v){bv, bv, bv, bv};
    }
#pragma unroll
    for (int ks = 0; ks < 2; ks++) {
        half8 A2 = *(const half8*)(tw + ks * 512 + fragoff);
#pragma unroll
        for (int nt = 0; nt < 4; nt++) {
            half8 B = *(const half8*)(wff + (ks * 4 + nt) * 512 + fragoff);
            c2[nt] = __builtin_amdgcn_mfma_f32_16x16x32_f16(A2, B, c2[nt], 0, 0, 0);
        }
    }

    // store: D elem (row = lh*4+r, col = nt*16+lr); 64B segments per (nt,r)
#pragma unroll
    for (int nt = 0; nt < 4; nt++) {
#pragma unroll
        for (int r = 0; r < 4; r++)
            out[(size_t)(vbase + lh * 4 + r) * 64 + nt * 16 + lr] = c2[nt][r];
    }
}

extern "C" void kernel_launch(void* const* d_in, const int* in_sizes, int n_in,
                              void* d_out, int out_size, void* d_ws, size_t ws_size,
                              hipStream_t stream) {
    const float* x  = (const float*)d_in[0];
    const float* W1 = (const float*)d_in[1];
    const float* b1 = (const float*)d_in[2];
    const float* W2 = (const float*)d_in[3];
    const float* b2 = (const float*)d_in[4];
    const float* W3 = (const float*)d_in[5];
    const float* b3 = (const float*)d_in[6];
    const float* Wf = (const float*)d_in[7];
    const float* bf = (const float*)d_in[8];
    const int*   ei = (const int*)d_in[9];

    const int N = in_sizes[0] / 8;   // 262144
    const int E = in_sizes[9] / 2;   // 2097152
    const int* srcv = ei;
    const int* dstv = ei + E;
    const int shift = 10;            // log2(NPB)

    // Workspace layout (64B-aligned chunks)
    char* p = (char*)d_ws;
    auto take = [&p](size_t bytes) { char* q = p; p += (bytes + 63) & ~size_t(63); return q; };
    int*   off   = (int*)take((size_t)(N + 16) * 4);
    float* dinv  = (float*)take((size_t)N * 4);
    int*   adj   = (int*)take((size_t)E * 4);
    int*   ghist = (int*)take(NB * 4);
    int*   bbase = (int*)take((NB + 1) * 4);
    int*   gcur  = (int*)take(NB * 4);
    _Float16* w3f = (_Float16*)take(32 * 64 * 2);      // frag-ordered fp16 W3
    _Float16* wff = (_Float16*)take(64 * 64 * 2);      // frag-ordered fp16 Wf
    char*  bufA  = take((size_t)N * 32 * 4);           // y0h (fp16, 4MB)
    char*  bufB  = take((size_t)N * 16 * 4);           // y1h (fp16, 8MB)
    char*  regX  = take((size_t)N * 32 * 2);           // 16MB: bedge (8MB) then y2b (fp16)
    unsigned int* bedge = (unsigned int*)regX;
    unsigned int* y2b   = (unsigned int*)regX;
    _Float16* y0h = (_Float16*)bufA;
    _Float16* y1h = (_Float16*)bufB;

    hipMemsetAsync(ghist, 0, NB * 4, stream);

    int nt = (E + TILE - 1) / TILE;  // 512 tiles
    hist_kernel<<<nt, 256, 0, stream>>>(dstv, ghist, E, shift);
    bscan_kernel<<<1, NB, 0, stream>>>(ghist, bbase, gcur, W3, Wf, w3f, wff);
    partition_kernel<<<nt, 256, 0, stream>>>(srcv, dstv, gcur, bedge, E, shift, NPB - 1);
    build_kernel<<<NB, 256, 0, stream>>>(bbase, bedge, x, off, dinv, adj, y0h);

    // L1: agg(y0h) + transform 8->16 -> y1h (fp16)
    aggt1_kernel<<<N / 256, 256, 0, stream>>>(y0h, off, adj, dinv, W1, b1, y1h);
    // L2: agg(y1h) + transform 16->32 -> y2b (fp16; overwrites dead bedge)
    aggt2_kernel<<<N / 256, 256, 0, stream>>>(y1h, off, adj, dinv, W2, b2, y2b);
    // L3: fused agg(y2b) + transform + FC -> out (no a3 round-trip)
    agg3t3fc_kernel<<<N / 64, 256, 0, stream>>>(y2b, off, adj, dinv, w3f, b3, wff, bf,
                                                (float*)d_out);
}